// Round 2
// baseline (1551.162 us; speedup 1.0000x reference)
//
#include <hip/hip_runtime.h>
#include <hip/hip_bf16.h>

// Problem constants
#define B_   4
#define T_   32
#define N_   370
#define E_   11840
#define E2_  12210          // E_ + N_ self loops
#define H_   64
#define G_   128            // B_*T_
#define GN_  47360          // G_*N_
#define BN_  1480           // B_*N_
#define NH_  23680          // N_*H_
#define KCH_ 2960           // NH_/8 k-chunk for MLP1

__device__ __forceinline__ float gelu_f(float x){
  return 0.5f * x * (1.0f + erff(x * 0.7071067811865475f));
}
__device__ __forceinline__ float wsum64(float v){
  #pragma unroll
  for (int m = 32; m > 0; m >>= 1) v += __shfl_xor(v, m, 64);
  return v;
}

// ---------- edge preprocessing ----------
__global__ void k_deg_count(const int* __restrict__ ei, const float* __restrict__ ew,
                            float* __restrict__ deg, int* __restrict__ counts){
  int e = blockIdx.x * 256 + threadIdx.x;
  if (e >= E2_) return;
  int dst = (e < E_) ? ei[E_ + e] : (e - E_);
  float w = (e < E_) ? ew[e] : 1.0f;
  atomicAdd(&deg[dst], w);
  atomicAdd(&counts[dst], 1);
}

__global__ void k_gnorm(const int* __restrict__ ei, const float* __restrict__ ew,
                        const float* __restrict__ deg, float* __restrict__ gnorm){
  int e = blockIdx.x * 256 + threadIdx.x;
  if (e >= E2_) return;
  int s = (e < E_) ? ei[e] : (e - E_);
  int d = (e < E_) ? ei[E_ + e] : (e - E_);
  float w = (e < E_) ? ew[e] : 1.0f;
  float ds = deg[s] > 0.f ? rsqrtf(deg[s]) : 0.f;
  float dd = deg[d] > 0.f ? rsqrtf(deg[d]) : 0.f;
  gnorm[e] = ds * w * dd;
}

__global__ void k_scan(const int* __restrict__ counts, int* __restrict__ offs,
                       int* __restrict__ cursor){
  if (threadIdx.x == 0 && blockIdx.x == 0){
    int acc = 0;
    for (int n = 0; n < N_; ++n){ offs[n] = acc; cursor[n] = acc; acc += counts[n]; }
    offs[N_] = acc;
  }
}

__global__ void k_fill(const int* __restrict__ ei, const float* __restrict__ gnorm,
                       int* __restrict__ cursor, int* __restrict__ csr_src,
                       float* __restrict__ csr_g){
  int e = blockIdx.x * 256 + threadIdx.x;
  if (e >= E2_) return;
  int s = (e < E_) ? ei[e] : (e - E_);
  int d = (e < E_) ? ei[E_ + e] : (e - E_);
  int pos = atomicAdd(&cursor[d], 1);
  csr_src[pos] = s;
  csr_g[pos] = gnorm[e];
}

// rows x 64  @  64 x 64 W -> rows x 64 ; 4 rows per 256-thread block
__global__ __launch_bounds__(256) void k_rowgemm(const float* __restrict__ in,
                                                 const float* __restrict__ W,
                                                 float* __restrict__ outp){
  __shared__ float Ws[64 * 64];
  __shared__ float rs[4][64];
  int tid = threadIdx.x;
  for (int i = tid; i < 4096; i += 256) Ws[i] = W[i];
  int r0 = blockIdx.x * 4;
  int rr = tid >> 6, cc = tid & 63;
  rs[rr][cc] = in[(size_t)(r0 + rr) * 64 + cc];
  __syncthreads();
  float acc = 0.f;
  #pragma unroll
  for (int i = 0; i < 64; ++i) acc += rs[rr][i] * Ws[i * 64 + cc];
  outp[(size_t)(r0 + rr) * 64 + cc] = acc;
}

// GCN aggregate: per (g,n) gather over incoming edges, + bias, GELU
__global__ __launch_bounds__(64) void k_gcn_agg(const float* __restrict__ hw,
    const int* __restrict__ csr_src, const int* __restrict__ offs,
    const float* __restrict__ csr_g, const float* __restrict__ b_gcn,
    float* __restrict__ gout){
  int gn = blockIdx.x;
  int g = gn / N_, n = gn % N_;
  int c = threadIdx.x;
  int o0 = offs[n], o1 = offs[n + 1];
  const float* hwg = hw + (size_t)g * N_ * 64;
  float acc = 0.f;
  for (int p = o0; p < o1; ++p)
    acc += csr_g[p] * hwg[(size_t)csr_src[p] * 64 + c];
  acc += b_gcn[c];
  gout[(size_t)gn * 64 + c] = gelu_f(acc);
}

// attention scores per (g,n,head)
__global__ void k_attn(const float* __restrict__ gh, const float* __restrict__ att_s,
                       const float* __restrict__ att_d, float* __restrict__ asrc,
                       float* __restrict__ adst){
  int idx = blockIdx.x * 256 + threadIdx.x;   // GN_*4 exact
  int head = idx & 3;
  int gn = idx >> 2;
  const float* row = gh + (size_t)gn * 64 + head * 16;
  float as = 0.f, ad = 0.f;
  #pragma unroll
  for (int d = 0; d < 16; ++d){
    float v = row[d];
    as += v * att_s[head * 16 + d];
    ad += v * att_d[head * 16 + d];
  }
  asrc[idx] = as;
  adst[idx] = ad;
}

// GAT aggregate (softmax over incoming edges) + bias + residual + LayerNorm, in-place on h
__global__ __launch_bounds__(64) void k_gat_agg(const float* __restrict__ gh,
    const float* __restrict__ asrc, const float* __restrict__ adst,
    const int* __restrict__ csr_src, const int* __restrict__ offs,
    const float* __restrict__ b_gat, const float* __restrict__ ln_g,
    const float* __restrict__ ln_b, float* __restrict__ h){
  int gn = blockIdx.x;
  int g = gn / N_, n = gn % N_;
  int c = threadIdx.x;
  int head = c >> 4;
  int o0 = offs[n], o1 = offs[n + 1];
  const float* as_g = asrc + (size_t)g * N_ * 4;
  float adv = adst[(size_t)gn * 4 + head];
  float m = -1e30f;
  for (int p = o0; p < o1; ++p){
    int s = csr_src[p];
    float v = as_g[s * 4 + head] + adv;
    v = v > 0.f ? v : 0.2f * v;
    m = fmaxf(m, v);
  }
  const float* gh_g = gh + (size_t)g * N_ * 64;
  float den = 0.f, acc = 0.f;
  for (int p = o0; p < o1; ++p){
    int s = csr_src[p];
    float v = as_g[s * 4 + head] + adv;
    v = v > 0.f ? v : 0.2f * v;
    float ex = expf(v - m);
    den += ex;
    acc += ex * gh_g[(size_t)s * 64 + c];
  }
  float outv = acc / den + b_gat[c];
  size_t hidx = (size_t)gn * 64 + c;
  float r = outv + h[hidx];
  float mu = wsum64(r) * (1.f / 64.f);
  float d = r - mu;
  float var = wsum64(d * d) * (1.f / 64.f);
  h[hidx] = d * rsqrtf(var + 1e-5f) * ln_g[c] + ln_b[c];
}

// (B,T,N,H) -> (B,N,H,T)
__global__ void k_transpose(const float* __restrict__ h, float* __restrict__ xt){
  int idx = blockIdx.x * 256 + threadIdx.x;   // B_*N_*64*32 exact
  int t = idx & 31;
  int ch = (idx >> 5) & 63;
  int n = (idx >> 11) % N_;
  int b = idx / (2048 * N_);
  xt[idx] = h[(((size_t)(b * T_ + t) * N_ + n) << 6) + ch];
}

// temporal conv layer: out = gelu(conv(x) + b) + x ; one block per (b,n)
__global__ __launch_bounds__(256) void k_tconv(const float* __restrict__ xin_g,
    const float* __restrict__ Wt, const float* __restrict__ bt,
    float* __restrict__ xout_g){
  __shared__ float xin[64 * 32];
  int bn = blockIdx.x;
  size_t base = (size_t)bn * 2048;
  int tid = threadIdx.x;
  for (int i = tid; i < 2048; i += 256) xin[i] = xin_g[base + i];
  __syncthreads();
  #pragma unroll
  for (int rep = 0; rep < 8; ++rep){
    int idx = tid + rep * 256;
    int ho = idx >> 5, t = idx & 31;
    float acc = bt[ho];
    const float* wr = Wt + ho * 320;
    for (int ci = 0; ci < 64; ++ci){
      const float* xc = xin + ci * 32;
      const float* w5 = wr + ci * 5;
      #pragma unroll
      for (int k = 0; k < 5; ++k){
        int tt = t + k - 2;
        float xv = (tt >= 0 && tt < 32) ? xc[tt] : 0.f;
        acc += xv * w5[k];
      }
    }
    xout_g[base + idx] = gelu_f(acc) + xin[idx];
  }
}

// MLP layer 1: y1[128,256] += z[128,23680-chunk] @ W1[chunk,256]; 4 rows/block
__global__ __launch_bounds__(256) void k_mlp1(const float* __restrict__ xt,
    const float* __restrict__ W1, float* __restrict__ y1){
  __shared__ float zs[4][KCH_];
  int rg = blockIdx.x;          // 0..31 row groups (4 rows each, same b)
  int kc = blockIdx.y;          // 0..7 k-chunks
  int b = rg >> 3;
  int t0 = (rg & 7) * 4;
  int base = kc * KCH_;
  for (int r = 0; r < 4; ++r){
    int t = t0 + r;
    for (int j = threadIdx.x; j < KCH_; j += 256){
      int jj = base + j;
      int n = jj >> 6, hh = jj & 63;
      zs[r][j] = xt[((size_t)(b * N_ + n) * 64 + hh) * 32 + t];
    }
  }
  __syncthreads();
  int col = threadIdx.x;
  float a0 = 0.f, a1 = 0.f, a2 = 0.f, a3 = 0.f;
  const float* wp = W1 + (size_t)base * 256 + col;
  for (int j = 0; j < KCH_; ++j){
    float w = wp[(size_t)j * 256];
    a0 += zs[0][j] * w;
    a1 += zs[1][j] * w;
    a2 += zs[2][j] * w;
    a3 += zs[3][j] * w;
  }
  int row0 = b * 32 + t0;
  atomicAdd(&y1[(size_t)(row0 + 0) * 256 + col], a0);
  atomicAdd(&y1[(size_t)(row0 + 1) * 256 + col], a1);
  atomicAdd(&y1[(size_t)(row0 + 2) * 256 + col], a2);
  atomicAdd(&y1[(size_t)(row0 + 3) * 256 + col], a3);
}

// MLP layer 2: out[128,64] = gelu(y1+b1) @ W2 + b2
__global__ __launch_bounds__(64) void k_mlp2(const float* __restrict__ y1,
    const float* __restrict__ b1, const float* __restrict__ W2,
    const float* __restrict__ b2, float* __restrict__ outp){
  __shared__ float a[256];
  int row = blockIdx.x, tid = threadIdx.x;
  for (int i = tid; i < 256; i += 64) a[i] = gelu_f(y1[(size_t)row * 256 + i] + b1[i]);
  __syncthreads();
  float acc = b2[tid];
  for (int i = 0; i < 256; ++i) acc += a[i] * W2[i * 64 + tid];
  outp[row * 64 + tid] = acc;
}

extern "C" void kernel_launch(void* const* d_in, const int* in_sizes, int n_in,
                              void* d_out, int out_size, void* d_ws, size_t ws_size,
                              hipStream_t stream){
  const float* x     = (const float*)d_in[0];
  const int*   ei    = (const int*)  d_in[1];
  const float* ew    = (const float*)d_in[2];
  const float* W_gcn = (const float*)d_in[3];
  const float* b_gcn = (const float*)d_in[4];
  const float* W_gat = (const float*)d_in[5];
  const float* att_s = (const float*)d_in[6];
  const float* att_d = (const float*)d_in[7];
  const float* b_gat = (const float*)d_in[8];
  const float* W_t   = (const float*)d_in[9];
  const float* b_t   = (const float*)d_in[10];
  const float* ln_g  = (const float*)d_in[11];
  const float* ln_b  = (const float*)d_in[12];
  const float* W1    = (const float*)d_in[13];
  const float* b1    = (const float*)d_in[14];
  const float* W2    = (const float*)d_in[15];
  const float* b2    = (const float*)d_in[16];
  float* outp = (float*)d_out;

  float* F = (float*)d_ws;
  size_t off = 0;
  float* deg   = F + off; off += 512;
  float* gnorm = F + off; off += 12288;
  float* csr_g = F + off; off += 12288;
  float* asrc  = F + off; off += 189440;
  float* adst  = F + off; off += 189440;
  float* y1    = F + off; off += 32768;
  float* h     = F + off; off += 3031040;
  float* bufB  = F + off; off += 3031040;   // hw / xt ping
  float* bufC  = F + off; off += 3031040;   // gbuf / xt pong
  float* bufD  = F + off; off += 3031040;   // gh
  int* I       = (int*)(F + off);
  int* counts  = I;
  int* offs    = I + 512;
  int* cursor  = I + 1024;
  int* csr_src = I + 1536;                  // E2_ entries

  hipMemsetAsync(deg, 0, 512 * sizeof(float), stream);
  hipMemsetAsync(counts, 0, 512 * sizeof(int), stream);
  hipMemsetAsync(y1, 0, 32768 * sizeof(float), stream);

  k_deg_count<<<48, 256, 0, stream>>>(ei, ew, deg, counts);
  k_gnorm<<<48, 256, 0, stream>>>(ei, ew, deg, gnorm);
  k_scan<<<1, 1, 0, stream>>>(counts, offs, cursor);
  k_fill<<<48, 256, 0, stream>>>(ei, gnorm, cursor, csr_src, csr_g);
  hipMemcpyAsync(h, x, (size_t)GN_ * 64 * sizeof(float), hipMemcpyDeviceToDevice, stream);

  for (int l = 0; l < 3; ++l){
    k_rowgemm<<<11840, 256, 0, stream>>>(h, W_gcn + l * 4096, bufB);
    k_gcn_agg<<<GN_, 64, 0, stream>>>(bufB, csr_src, offs, csr_g, b_gcn + l * 64, bufC);
    k_rowgemm<<<11840, 256, 0, stream>>>(bufC, W_gat + l * 4096, bufD);
    k_attn<<<740, 256, 0, stream>>>(bufD, att_s + l * 64, att_d + l * 64, asrc, adst);
    k_gat_agg<<<GN_, 64, 0, stream>>>(bufD, asrc, adst, csr_src, offs,
                                      b_gat + l * 64, ln_g + l * 64, ln_b + l * 64, h);
  }

  k_transpose<<<11840, 256, 0, stream>>>(h, bufB);
  k_tconv<<<BN_, 256, 0, stream>>>(bufB, W_t + 0 * 20480, b_t + 0 * 64, bufC);
  k_tconv<<<BN_, 256, 0, stream>>>(bufC, W_t + 1 * 20480, b_t + 1 * 64, bufB);
  k_tconv<<<BN_, 256, 0, stream>>>(bufB, W_t + 2 * 20480, b_t + 2 * 64, bufC);

  dim3 g1(32, 8);
  k_mlp1<<<g1, 256, 0, stream>>>(bufC, W1, y1);
  k_mlp2<<<128, 64, 0, stream>>>(y1, b1, W2, b2, outp);
}

// Round 3
// 1466.781 us; speedup vs baseline: 1.0575x; 1.0575x over previous
//
#include <hip/hip_runtime.h>
#include <hip/hip_bf16.h>

// Problem constants
#define B_   4
#define T_   32
#define N_   370
#define E_   11840
#define E2_  12210          // E_ + N_ self loops
#define H_   64
#define G_   128            // B_*T_
#define GN_  47360          // G_*N_
#define BN_  1480           // B_*N_
#define NH_  23680          // N_*H_

__device__ __forceinline__ float gelu_f(float x){
  return 0.5f * x * (1.0f + erff(x * 0.7071067811865475f));
}
__device__ __forceinline__ float wsum64(float v){
  #pragma unroll
  for (int m = 32; m > 0; m >>= 1) v += __shfl_xor(v, m, 64);
  return v;
}

// ---------- edge preprocessing ----------
__global__ void k_deg_count(const int* __restrict__ ei, const float* __restrict__ ew,
                            float* __restrict__ deg, int* __restrict__ counts){
  int e = blockIdx.x * 256 + threadIdx.x;
  if (e >= E2_) return;
  int dst = (e < E_) ? ei[E_ + e] : (e - E_);
  float w = (e < E_) ? ew[e] : 1.0f;
  atomicAdd(&deg[dst], w);
  atomicAdd(&counts[dst], 1);
}

__global__ void k_gnorm(const int* __restrict__ ei, const float* __restrict__ ew,
                        const float* __restrict__ deg, float* __restrict__ gnorm){
  int e = blockIdx.x * 256 + threadIdx.x;
  if (e >= E2_) return;
  int s = (e < E_) ? ei[e] : (e - E_);
  int d = (e < E_) ? ei[E_ + e] : (e - E_);
  float w = (e < E_) ? ew[e] : 1.0f;
  float ds = deg[s] > 0.f ? rsqrtf(deg[s]) : 0.f;
  float dd = deg[d] > 0.f ? rsqrtf(deg[d]) : 0.f;
  gnorm[e] = ds * w * dd;
}

// wave-parallel exclusive scan over counts (one wave)
__global__ void k_scan(const int* __restrict__ counts, int* __restrict__ offs,
                       int* __restrict__ cursor){
  int lane = threadIdx.x;
  int run = 0;
  for (int c0 = 0; c0 < N_; c0 += 64){
    int n = c0 + lane;
    int v = (n < N_) ? counts[n] : 0;
    int s = v;
    #pragma unroll
    for (int m = 1; m < 64; m <<= 1){
      int t = __shfl_up(s, m, 64);
      if (lane >= m) s += t;
    }
    int excl = run + s - v;
    if (n < N_){ offs[n] = excl; cursor[n] = excl; }
    run += __shfl(s, 63, 64);
  }
  if (lane == 0) offs[N_] = run;
}

__global__ void k_fill(const int* __restrict__ ei, const float* __restrict__ gnorm,
                       int* __restrict__ cursor, int* __restrict__ csr_src,
                       float* __restrict__ csr_g){
  int e = blockIdx.x * 256 + threadIdx.x;
  if (e >= E2_) return;
  int s = (e < E_) ? ei[e] : (e - E_);
  int d = (e < E_) ? ei[E_ + e] : (e - E_);
  int pos = atomicAdd(&cursor[d], 1);
  csr_src[pos] = s;
  csr_g[pos] = gnorm[e];
}

// rows x 64 @ 64 x 64 -> rows x 64 ; 32 rows/block, 4x2 register tile
__global__ __launch_bounds__(256) void k_rowgemm(const float* __restrict__ in,
                                                 const float* __restrict__ W,
                                                 float* __restrict__ outp){
  __shared__ float Ws[64 * 64];     // [k][col]
  __shared__ float rsT[64 * 36];    // [k][row], padded to 36
  int tid = threadIdx.x;
  size_t r0 = (size_t)blockIdx.x * 32;
  for (int i = tid; i < 4096; i += 256) Ws[i] = W[i];
  for (int i = tid; i < 2048; i += 256){
    int r = i >> 6, k = i & 63;
    rsT[k * 36 + r] = in[(r0 + r) * 64 + k];
  }
  __syncthreads();
  int cp = tid & 31;       // col pair id
  int rg = tid >> 5;       // row group 0..7 (4 rows each)
  int c0 = cp * 2;
  int rr0 = rg * 4;
  float2 acc0 = {0.f,0.f}, acc1 = {0.f,0.f}, acc2 = {0.f,0.f}, acc3 = {0.f,0.f};
  #pragma unroll 4
  for (int k = 0; k < 64; ++k){
    float4 rv = *(const float4*)&rsT[k * 36 + rr0];
    float2 wv = *(const float2*)&Ws[k * 64 + c0];
    acc0.x += rv.x * wv.x; acc0.y += rv.x * wv.y;
    acc1.x += rv.y * wv.x; acc1.y += rv.y * wv.y;
    acc2.x += rv.z * wv.x; acc2.y += rv.z * wv.y;
    acc3.x += rv.w * wv.x; acc3.y += rv.w * wv.y;
  }
  *(float2*)&outp[(r0 + rr0 + 0) * 64 + c0] = acc0;
  *(float2*)&outp[(r0 + rr0 + 1) * 64 + c0] = acc1;
  *(float2*)&outp[(r0 + rr0 + 2) * 64 + c0] = acc2;
  *(float2*)&outp[(r0 + rr0 + 3) * 64 + c0] = acc3;
}

// GCN aggregate: 4 (g,n) per block, one wave each
__global__ __launch_bounds__(256) void k_gcn_agg(const float* __restrict__ hw,
    const int* __restrict__ csr_src, const int* __restrict__ offs,
    const float* __restrict__ csr_g, const float* __restrict__ b_gcn,
    float* __restrict__ gout){
  int gn = blockIdx.x * 4 + (threadIdx.x >> 6);
  int c = threadIdx.x & 63;
  int g = gn / N_, n = gn - g * N_;
  int o0 = offs[n], o1 = offs[n + 1];
  const float* hwg = hw + (size_t)g * N_ * 64;
  float acc = 0.f;
  for (int p = o0; p < o1; ++p)
    acc += csr_g[p] * hwg[(size_t)csr_src[p] * 64 + c];
  acc += b_gcn[c];
  gout[(size_t)gn * 64 + c] = gelu_f(acc);
}

// attention scores per (g,n,head)
__global__ void k_attn(const float* __restrict__ gh, const float* __restrict__ att_s,
                       const float* __restrict__ att_d, float* __restrict__ asrc,
                       float* __restrict__ adst){
  int idx = blockIdx.x * 256 + threadIdx.x;   // GN_*4 exact
  int head = idx & 3;
  int gn = idx >> 2;
  const float* row = gh + (size_t)gn * 64 + head * 16;
  float as = 0.f, ad = 0.f;
  #pragma unroll
  for (int d = 0; d < 16; ++d){
    float v = row[d];
    as += v * att_s[head * 16 + d];
    ad += v * att_d[head * 16 + d];
  }
  asrc[idx] = as;
  adst[idx] = ad;
}

// GAT aggregate + bias + residual + LayerNorm; 4 (g,n) per block
__global__ __launch_bounds__(256) void k_gat_agg(const float* __restrict__ gh,
    const float* __restrict__ asrc, const float* __restrict__ adst,
    const int* __restrict__ csr_src, const int* __restrict__ offs,
    const float* __restrict__ b_gat, const float* __restrict__ ln_g,
    const float* __restrict__ ln_b, float* __restrict__ h){
  int gn = blockIdx.x * 4 + (threadIdx.x >> 6);
  int c = threadIdx.x & 63;
  int g = gn / N_, n = gn - g * N_;
  int head = c >> 4;
  int o0 = offs[n], o1 = offs[n + 1];
  const float* as_g = asrc + (size_t)g * N_ * 4;
  float adv = adst[(size_t)gn * 4 + head];
  float m = -1e30f;
  for (int p = o0; p < o1; ++p){
    int s = csr_src[p];
    float v = as_g[s * 4 + head] + adv;
    v = v > 0.f ? v : 0.2f * v;
    m = fmaxf(m, v);
  }
  const float* gh_g = gh + (size_t)g * N_ * 64;
  float den = 0.f, acc = 0.f;
  for (int p = o0; p < o1; ++p){
    int s = csr_src[p];
    float v = as_g[s * 4 + head] + adv;
    v = v > 0.f ? v : 0.2f * v;
    float ex = expf(v - m);
    den += ex;
    acc += ex * gh_g[(size_t)s * 64 + c];
  }
  float outv = acc / den + b_gat[c];
  size_t hidx = (size_t)gn * 64 + c;
  float r = outv + h[hidx];
  float mu = wsum64(r) * (1.f / 64.f);
  float d = r - mu;
  float var = wsum64(d * d) * (1.f / 64.f);
  h[hidx] = d * rsqrtf(var + 1e-5f) * ln_g[c] + ln_b[c];
}

// (B,T,N,H) -> (B*N, H, T) via LDS tile; one block per (b,n)
__global__ __launch_bounds__(256) void k_transpose2(const float* __restrict__ h,
                                                    float* __restrict__ xt){
  __shared__ float tile[64 * 33];
  int bn = blockIdx.x;
  int b = bn / N_, n = bn - b * N_;
  int tid = threadIdx.x;
  for (int i = tid; i < 2048; i += 256){
    int t = i >> 6, ch = i & 63;
    tile[ch * 33 + t] = h[((size_t)(b * T_ + t) * N_ + n) * 64 + ch];
  }
  __syncthreads();
  size_t base = (size_t)bn * 2048;
  for (int i = tid; i < 2048; i += 256){
    int ho = i >> 5, t = i & 31;
    xt[base + i] = tile[ho * 33 + t];
  }
}

// temporal conv layer: out = gelu(conv(x)+b)+x ; one block per (b,n)
// x tile padded [64][36] (2 zeros each side), W transposed in LDS [320][ho] pad 65
__global__ __launch_bounds__(256) void k_tconv(const float* __restrict__ xin_g,
    const float* __restrict__ Wt, const float* __restrict__ bt,
    float* __restrict__ xout_g){
  __shared__ float xs2[64 * 36];
  __shared__ float WsT[320 * 65];
  int bn = blockIdx.x;
  size_t base = (size_t)bn * 2048;
  int tid = threadIdx.x;
  for (int i = tid; i < 64 * 36; i += 256) xs2[i] = 0.f;
  for (int i = tid; i < 20480; i += 256){
    int ho = i / 320, j = i - ho * 320;
    WsT[j * 65 + ho] = Wt[i];
  }
  __syncthreads();
  for (int i = tid; i < 2048; i += 256){
    int ci = i >> 5, t = i & 31;
    xs2[ci * 36 + 2 + t] = xin_g[base + i];
  }
  __syncthreads();
  int tq = tid >> 6;        // wave id -> t block of 8
  int ho = tid & 63;
  int t0 = tq * 8;
  float bv = bt[ho];
  float acc[8];
  #pragma unroll
  for (int r = 0; r < 8; ++r) acc[r] = bv;
  for (int ci = 0; ci < 64; ++ci){
    const float* xr = &xs2[ci * 36 + t0];   // xr[q] = x[ci][t0+q-2]
    float4 xa = *(const float4*)&xr[0];
    float4 xb = *(const float4*)&xr[4];
    float4 xc = *(const float4*)&xr[8];
    float xw[12] = {xa.x, xa.y, xa.z, xa.w, xb.x, xb.y, xb.z, xb.w,
                    xc.x, xc.y, xc.z, xc.w};
    const float* wr = &WsT[(ci * 5) * 65 + ho];
    #pragma unroll
    for (int k = 0; k < 5; ++k){
      float w = wr[k * 65];
      #pragma unroll
      for (int r = 0; r < 8; ++r) acc[r] += xw[r + k] * w;
    }
  }
  #pragma unroll
  for (int r = 0; r < 8; ++r){
    int t = t0 + r;
    xout_g[base + ho * 32 + t] = gelu_f(acc[r]) + xs2[ho * 36 + 2 + t];
  }
}

// (B*N, H, T) -> z[(b*T+t)][N*H] via LDS tile
__global__ __launch_bounds__(256) void k_zshape(const float* __restrict__ xt,
                                                float* __restrict__ z){
  __shared__ float tile[64 * 33];
  int bn = blockIdx.x;
  int b = bn / N_, n = bn - b * N_;
  int tid = threadIdx.x;
  size_t base = (size_t)bn * 2048;
  for (int i = tid; i < 2048; i += 256){
    int ho = i >> 5, t = i & 31;
    tile[ho * 33 + t] = xt[base + i];
  }
  __syncthreads();
  for (int i = tid; i < 2048; i += 256){
    int t = i >> 6, ch = i & 63;
    z[(size_t)(b * T_ + t) * NH_ + n * 64 + ch] = tile[ch * 33 + t];
  }
}

// MLP layer 1: y1[128,256] += z[16-row tile, 370-chunk] @ W1[chunk,256]
// grid (8 rowgroups, 64 kchunks); 4x4 register tile per thread
__global__ __launch_bounds__(256) void k_mlp1(const float* __restrict__ z,
    const float* __restrict__ W1, float* __restrict__ y1){
  __shared__ float zs[370 * 20];    // [j][r], row stride 20 (16B-aligned)
  int rg = blockIdx.x;              // 0..7
  int kc = blockIdx.y;              // 0..63
  int b = rg >> 1;
  int t0 = (rg & 1) * 16;
  int base = kc * 370;
  int tid = threadIdx.x;
  for (int i = tid; i < 370 * 16; i += 256){
    int r = i / 370, j = i - r * 370;
    zs[j * 20 + r] = z[(size_t)(b * T_ + t0 + r) * NH_ + base + j];
  }
  __syncthreads();
  int cg = tid >> 6;        // wave id -> row sub-block of 4
  int r0 = cg * 4;
  int c0 = (tid & 63) * 4;
  float4 acc0 = {0,0,0,0}, acc1 = {0,0,0,0}, acc2 = {0,0,0,0}, acc3 = {0,0,0,0};
  const float* wbase = W1 + (size_t)base * 256 + c0;
  #pragma unroll 2
  for (int j = 0; j < 370; ++j){
    float4 zv = *(const float4*)&zs[j * 20 + r0];
    float4 wv = *(const float4*)&wbase[(size_t)j * 256];
    acc0.x += zv.x * wv.x; acc0.y += zv.x * wv.y; acc0.z += zv.x * wv.z; acc0.w += zv.x * wv.w;
    acc1.x += zv.y * wv.x; acc1.y += zv.y * wv.y; acc1.z += zv.y * wv.z; acc1.w += zv.y * wv.w;
    acc2.x += zv.z * wv.x; acc2.y += zv.z * wv.y; acc2.z += zv.z * wv.z; acc2.w += zv.z * wv.w;
    acc3.x += zv.w * wv.x; acc3.y += zv.w * wv.y; acc3.z += zv.w * wv.z; acc3.w += zv.w * wv.w;
  }
  float4 av[4] = {acc0, acc1, acc2, acc3};
  #pragma unroll
  for (int rr = 0; rr < 4; ++rr){
    int row = b * T_ + t0 + r0 + rr;
    float* yp = &y1[(size_t)row * 256 + c0];
    atomicAdd(&yp[0], av[rr].x);
    atomicAdd(&yp[1], av[rr].y);
    atomicAdd(&yp[2], av[rr].z);
    atomicAdd(&yp[3], av[rr].w);
  }
}

// MLP layer 2: out[128,64] = gelu(y1+b1) @ W2 + b2
__global__ __launch_bounds__(64) void k_mlp2(const float* __restrict__ y1,
    const float* __restrict__ b1, const float* __restrict__ W2,
    const float* __restrict__ b2, float* __restrict__ outp){
  __shared__ float a[256];
  int row = blockIdx.x, tid = threadIdx.x;
  for (int i = tid; i < 256; i += 64) a[i] = gelu_f(y1[(size_t)row * 256 + i] + b1[i]);
  __syncthreads();
  float acc = b2[tid];
  for (int i = 0; i < 256; ++i) acc += a[i] * W2[i * 64 + tid];
  outp[row * 64 + tid] = acc;
}

extern "C" void kernel_launch(void* const* d_in, const int* in_sizes, int n_in,
                              void* d_out, int out_size, void* d_ws, size_t ws_size,
                              hipStream_t stream){
  const float* x     = (const float*)d_in[0];
  const int*   ei    = (const int*)  d_in[1];
  const float* ew    = (const float*)d_in[2];
  const float* W_gcn = (const float*)d_in[3];
  const float* b_gcn = (const float*)d_in[4];
  const float* W_gat = (const float*)d_in[5];
  const float* att_s = (const float*)d_in[6];
  const float* att_d = (const float*)d_in[7];
  const float* b_gat = (const float*)d_in[8];
  const float* W_t   = (const float*)d_in[9];
  const float* b_t   = (const float*)d_in[10];
  const float* ln_g  = (const float*)d_in[11];
  const float* ln_b  = (const float*)d_in[12];
  const float* W1    = (const float*)d_in[13];
  const float* b1    = (const float*)d_in[14];
  const float* W2    = (const float*)d_in[15];
  const float* b2    = (const float*)d_in[16];
  float* outp = (float*)d_out;

  float* F = (float*)d_ws;
  size_t off = 0;
  float* deg   = F + off; off += 512;
  float* gnorm = F + off; off += 12288;
  float* csr_g = F + off; off += 12288;
  float* asrc  = F + off; off += 189440;
  float* adst  = F + off; off += 189440;
  float* y1    = F + off; off += 32768;
  float* h     = F + off; off += 3031040;
  float* bufB  = F + off; off += 3031040;   // hw / xt ping
  float* bufC  = F + off; off += 3031040;   // g / xt pong
  float* bufD  = F + off; off += 3031040;   // gh / z
  int* I       = (int*)(F + off);
  int* counts  = I;
  int* offs    = I + 512;
  int* cursor  = I + 1024;
  int* csr_src = I + 1536;                  // E2_ entries

  hipMemsetAsync(deg, 0, 512 * sizeof(float), stream);
  hipMemsetAsync(counts, 0, 512 * sizeof(int), stream);
  hipMemsetAsync(y1, 0, 32768 * sizeof(float), stream);

  k_deg_count<<<48, 256, 0, stream>>>(ei, ew, deg, counts);
  k_gnorm<<<48, 256, 0, stream>>>(ei, ew, deg, gnorm);
  k_scan<<<1, 64, 0, stream>>>(counts, offs, cursor);
  k_fill<<<48, 256, 0, stream>>>(ei, gnorm, cursor, csr_src, csr_g);
  hipMemcpyAsync(h, x, (size_t)GN_ * 64 * sizeof(float), hipMemcpyDeviceToDevice, stream);

  for (int l = 0; l < 3; ++l){
    k_rowgemm<<<1480, 256, 0, stream>>>(h, W_gcn + l * 4096, bufB);
    k_gcn_agg<<<11840, 256, 0, stream>>>(bufB, csr_src, offs, csr_g, b_gcn + l * 64, bufC);
    k_rowgemm<<<1480, 256, 0, stream>>>(bufC, W_gat + l * 4096, bufD);
    k_attn<<<740, 256, 0, stream>>>(bufD, att_s + l * 64, att_d + l * 64, asrc, adst);
    k_gat_agg<<<11840, 256, 0, stream>>>(bufD, asrc, adst, csr_src, offs,
                                         b_gat + l * 64, ln_g + l * 64, ln_b + l * 64, h);
  }

  k_transpose2<<<BN_, 256, 0, stream>>>(h, bufB);
  k_tconv<<<BN_, 256, 0, stream>>>(bufB, W_t + 0 * 20480, b_t + 0 * 64, bufC);
  k_tconv<<<BN_, 256, 0, stream>>>(bufC, W_t + 1 * 20480, b_t + 1 * 64, bufB);
  k_tconv<<<BN_, 256, 0, stream>>>(bufB, W_t + 2 * 20480, b_t + 2 * 64, bufC);
  k_zshape<<<BN_, 256, 0, stream>>>(bufC, bufD);

  dim3 g1(8, 64);
  k_mlp1<<<g1, 256, 0, stream>>>(bufD, W1, y1);
  k_mlp2<<<128, 64, 0, stream>>>(y1, b1, W2, b2, outp);
}

// Round 4
// 1351.415 us; speedup vs baseline: 1.1478x; 1.0854x over previous
//
#include <hip/hip_runtime.h>
#include <hip/hip_bf16.h>

// Problem constants
#define B_   4
#define T_   32
#define N_   370
#define E_   11840
#define E2_  12210          // E_ + N_ self loops
#define H_   64
#define G_   128            // B_*T_
#define GN_  47360          // G_*N_
#define BN_  1480           // B_*N_
#define NH_  23680          // N_*H_

__device__ __forceinline__ float gelu_f(float x){
  return 0.5f * x * (1.0f + erff(x * 0.7071067811865475f));
}
__device__ __forceinline__ float wsum64(float v){
  #pragma unroll
  for (int m = 32; m > 0; m >>= 1) v += __shfl_xor(v, m, 64);
  return v;
}

// ---------- edge preprocessing ----------
__global__ void k_deg_count(const int* __restrict__ ei, const float* __restrict__ ew,
                            float* __restrict__ deg, int* __restrict__ counts){
  int e = blockIdx.x * 256 + threadIdx.x;
  if (e >= E2_) return;
  int dst = (e < E_) ? ei[E_ + e] : (e - E_);
  float w = (e < E_) ? ew[e] : 1.0f;
  atomicAdd(&deg[dst], w);
  atomicAdd(&counts[dst], 1);
}

__global__ void k_gnorm(const int* __restrict__ ei, const float* __restrict__ ew,
                        const float* __restrict__ deg, float* __restrict__ gnorm){
  int e = blockIdx.x * 256 + threadIdx.x;
  if (e >= E2_) return;
  int s = (e < E_) ? ei[e] : (e - E_);
  int d = (e < E_) ? ei[E_ + e] : (e - E_);
  float w = (e < E_) ? ew[e] : 1.0f;
  float ds = deg[s] > 0.f ? rsqrtf(deg[s]) : 0.f;
  float dd = deg[d] > 0.f ? rsqrtf(deg[d]) : 0.f;
  gnorm[e] = ds * w * dd;
}

// wave-parallel exclusive scan over counts (one wave)
__global__ void k_scan(const int* __restrict__ counts, int* __restrict__ offs,
                       int* __restrict__ cursor){
  int lane = threadIdx.x;
  int run = 0;
  for (int c0 = 0; c0 < N_; c0 += 64){
    int n = c0 + lane;
    int v = (n < N_) ? counts[n] : 0;
    int s = v;
    #pragma unroll
    for (int m = 1; m < 64; m <<= 1){
      int t = __shfl_up(s, m, 64);
      if (lane >= m) s += t;
    }
    int excl = run + s - v;
    if (n < N_){ offs[n] = excl; cursor[n] = excl; }
    run += __shfl(s, 63, 64);
  }
  if (lane == 0) offs[N_] = run;
}

// stores PRE-SCALED source offset s*64 (element offset of row start)
__global__ void k_fill(const int* __restrict__ ei, const float* __restrict__ gnorm,
                       int* __restrict__ cursor, int* __restrict__ csr_soff,
                       float* __restrict__ csr_g){
  int e = blockIdx.x * 256 + threadIdx.x;
  if (e >= E2_) return;
  int s = (e < E_) ? ei[e] : (e - E_);
  int d = (e < E_) ? ei[E_ + e] : (e - E_);
  int pos = atomicAdd(&cursor[d], 1);
  csr_soff[pos] = s * 64;
  csr_g[pos] = gnorm[e];
}

// rows x 64 @ 64 x 64 -> rows x 64 ; 32 rows/block, 4x2 register tile
__global__ __launch_bounds__(256) void k_rowgemm(const float* __restrict__ in,
                                                 const float* __restrict__ W,
                                                 float* __restrict__ outp){
  __shared__ float Ws[64 * 64];     // [k][col]
  __shared__ float rsT[64 * 36];    // [k][row], padded to 36
  int tid = threadIdx.x;
  size_t r0 = (size_t)blockIdx.x * 32;
  for (int i = tid; i < 4096; i += 256) Ws[i] = W[i];
  for (int i = tid; i < 2048; i += 256){
    int r = i >> 6, k = i & 63;
    rsT[k * 36 + r] = in[(r0 + r) * 64 + k];
  }
  __syncthreads();
  int cp = tid & 31;       // col pair id
  int rg = tid >> 5;       // row group 0..7 (4 rows each)
  int c0 = cp * 2;
  int rr0 = rg * 4;
  float2 acc0 = {0.f,0.f}, acc1 = {0.f,0.f}, acc2 = {0.f,0.f}, acc3 = {0.f,0.f};
  #pragma unroll 4
  for (int k = 0; k < 64; ++k){
    float4 rv = *(const float4*)&rsT[k * 36 + rr0];
    float2 wv = *(const float2*)&Ws[k * 64 + c0];
    acc0.x += rv.x * wv.x; acc0.y += rv.x * wv.y;
    acc1.x += rv.y * wv.x; acc1.y += rv.y * wv.y;
    acc2.x += rv.z * wv.x; acc2.y += rv.z * wv.y;
    acc3.x += rv.w * wv.x; acc3.y += rv.w * wv.y;
  }
  *(float2*)&outp[(r0 + rr0 + 0) * 64 + c0] = acc0;
  *(float2*)&outp[(r0 + rr0 + 1) * 64 + c0] = acc1;
  *(float2*)&outp[(r0 + rr0 + 2) * 64 + c0] = acc2;
  *(float2*)&outp[(r0 + rr0 + 3) * 64 + c0] = acc3;
}

// GCN aggregate: 4 (g,n) per block, one wave each
__global__ __launch_bounds__(256) void k_gcn_agg(const float* __restrict__ hw,
    const int* __restrict__ csr_soff, const int* __restrict__ offs,
    const float* __restrict__ csr_g, const float* __restrict__ b_gcn,
    float* __restrict__ gout){
  int gn = blockIdx.x * 4 + (threadIdx.x >> 6);
  int c = threadIdx.x & 63;
  int g = gn / N_, n = gn - g * N_;
  int o0 = offs[n], o1 = offs[n + 1];
  const float* hwg = hw + (size_t)g * (N_ * 64);
  float acc = 0.f;
  for (int p = o0; p < o1; ++p)
    acc += csr_g[p] * hwg[csr_soff[p] + c];
  acc += b_gcn[c];
  gout[(size_t)gn * 64 + c] = gelu_f(acc);
}

// attention scores per (g,n,head)
__global__ void k_attn(const float* __restrict__ gh, const float* __restrict__ att_s,
                       const float* __restrict__ att_d, float* __restrict__ asrc,
                       float* __restrict__ adst){
  int idx = blockIdx.x * 256 + threadIdx.x;   // GN_*4 exact
  int head = idx & 3;
  int gn = idx >> 2;
  const float* row = gh + (size_t)gn * 64 + head * 16;
  float as = 0.f, ad = 0.f;
  #pragma unroll
  for (int d = 0; d < 16; ++d){
    float v = row[d];
    as += v * att_s[head * 16 + d];
    ad += v * att_d[head * 16 + d];
  }
  asrc[idx] = as;
  adst[idx] = ad;
}

// per (g,n,head): softmax max+denominator over incoming edges;
// writes UNNORMALIZED exp weights alpha[g][p][head] and invden[g][n][head]
__global__ void k_alpha(const float* __restrict__ asrc, const float* __restrict__ adst,
                        const int* __restrict__ csr_soff, const int* __restrict__ offs,
                        float* __restrict__ alpha, float* __restrict__ invden){
  int idx = blockIdx.x * 256 + threadIdx.x;   // (g*N+n)*4+head, GN_*4 exact
  int head = idx & 3;
  int gn = idx >> 2;
  int g = gn / N_, n = gn - g * N_;
  int o0 = offs[n], o1 = offs[n + 1];
  const float* as_g = asrc + (size_t)g * (N_ * 4);
  float adv = adst[idx];
  float m = -1e30f;
  for (int p = o0; p < o1; ++p){
    int s4 = csr_soff[p] >> 4;           // s*4
    float v = as_g[s4 + head] + adv;
    v = v > 0.f ? v : 0.2f * v;
    m = fmaxf(m, v);
  }
  float* al_g = alpha + (size_t)g * (E2_ * 4);
  float den = 0.f;
  for (int p = o0; p < o1; ++p){
    int s4 = csr_soff[p] >> 4;
    float v = as_g[s4 + head] + adv;
    v = v > 0.f ? v : 0.2f * v;
    float ex = expf(v - m);
    den += ex;
    al_g[p * 4 + head] = ex;
  }
  invden[idx] = 1.f / den;
}

// GAT aggregate (single pass, precomputed alpha) + bias + residual + LayerNorm
__global__ __launch_bounds__(256) void k_gat_agg(const float* __restrict__ gh,
    const float* __restrict__ alpha, const float* __restrict__ invden,
    const int* __restrict__ csr_soff, const int* __restrict__ offs,
    const float* __restrict__ b_gat, const float* __restrict__ ln_g,
    const float* __restrict__ ln_b, float* __restrict__ h){
  int gn = blockIdx.x * 4 + (threadIdx.x >> 6);
  int c = threadIdx.x & 63;
  int g = gn / N_, n = gn - g * N_;
  int head = c >> 4;
  int o0 = offs[n], o1 = offs[n + 1];
  const float* gh_g = gh + (size_t)g * (N_ * 64);
  const float* al_g = alpha + (size_t)g * (E2_ * 4);
  float acc = 0.f;
  for (int p = o0; p < o1; ++p)
    acc += al_g[p * 4 + head] * gh_g[csr_soff[p] + c];
  float outv = acc * invden[gn * 4 + head] + b_gat[c];
  size_t hidx = (size_t)gn * 64 + c;
  float r = outv + h[hidx];
  float mu = wsum64(r) * (1.f / 64.f);
  float d = r - mu;
  float var = wsum64(d * d) * (1.f / 64.f);
  h[hidx] = d * rsqrtf(var + 1e-5f) * ln_g[c] + ln_b[c];
}

// (B,T,N,H) -> (B*N, H, T) via LDS tile; one block per (b,n)
__global__ __launch_bounds__(256) void k_transpose2(const float* __restrict__ h,
                                                    float* __restrict__ xt){
  __shared__ float tile[64 * 33];
  int bn = blockIdx.x;
  int b = bn / N_, n = bn - b * N_;
  int tid = threadIdx.x;
  for (int i = tid; i < 2048; i += 256){
    int t = i >> 6, ch = i & 63;
    tile[ch * 33 + t] = h[((size_t)(b * T_ + t) * N_ + n) * 64 + ch];
  }
  __syncthreads();
  size_t base = (size_t)bn * 2048;
  for (int i = tid; i < 2048; i += 256){
    int ho = i >> 5, t = i & 31;
    xt[base + i] = tile[ho * 33 + t];
  }
}

// temporal conv layer: out = gelu(conv(x)+b)+x ; one block per (b,n)
__global__ __launch_bounds__(256) void k_tconv(const float* __restrict__ xin_g,
    const float* __restrict__ Wt, const float* __restrict__ bt,
    float* __restrict__ xout_g){
  __shared__ float xs2[64 * 36];
  __shared__ float WsT[320 * 65];
  int bn = blockIdx.x;
  size_t base = (size_t)bn * 2048;
  int tid = threadIdx.x;
  for (int i = tid; i < 64 * 36; i += 256) xs2[i] = 0.f;
  for (int i = tid; i < 20480; i += 256){
    int ho = i / 320, j = i - ho * 320;
    WsT[j * 65 + ho] = Wt[i];
  }
  __syncthreads();
  for (int i = tid; i < 2048; i += 256){
    int ci = i >> 5, t = i & 31;
    xs2[ci * 36 + 2 + t] = xin_g[base + i];
  }
  __syncthreads();
  int tq = tid >> 6;        // wave id -> t block of 8
  int ho = tid & 63;
  int t0 = tq * 8;
  float bv = bt[ho];
  float acc[8];
  #pragma unroll
  for (int r = 0; r < 8; ++r) acc[r] = bv;
  for (int ci = 0; ci < 64; ++ci){
    const float* xr = &xs2[ci * 36 + t0];   // xr[q] = x[ci][t0+q-2]
    float4 xa = *(const float4*)&xr[0];
    float4 xb = *(const float4*)&xr[4];
    float4 xc = *(const float4*)&xr[8];
    float xw[12] = {xa.x, xa.y, xa.z, xa.w, xb.x, xb.y, xb.z, xb.w,
                    xc.x, xc.y, xc.z, xc.w};
    const float* wr = &WsT[(ci * 5) * 65 + ho];
    #pragma unroll
    for (int k = 0; k < 5; ++k){
      float w = wr[k * 65];
      #pragma unroll
      for (int r = 0; r < 8; ++r) acc[r] += xw[r + k] * w;
    }
  }
  #pragma unroll
  for (int r = 0; r < 8; ++r){
    int t = t0 + r;
    xout_g[base + ho * 32 + t] = gelu_f(acc[r]) + xs2[ho * 36 + 2 + t];
  }
}

// (B*N, H, T) -> z[(b*T+t)][N*H] via LDS tile
__global__ __launch_bounds__(256) void k_zshape(const float* __restrict__ xt,
                                                float* __restrict__ z){
  __shared__ float tile[64 * 33];
  int bn = blockIdx.x;
  int b = bn / N_, n = bn - b * N_;
  int tid = threadIdx.x;
  size_t base = (size_t)bn * 2048;
  for (int i = tid; i < 2048; i += 256){
    int ho = i >> 5, t = i & 31;
    tile[ho * 33 + t] = xt[base + i];
  }
  __syncthreads();
  for (int i = tid; i < 2048; i += 256){
    int t = i >> 6, ch = i & 63;
    z[(size_t)(b * T_ + t) * NH_ + n * 64 + ch] = tile[ch * 33 + t];
  }
}

// MLP layer 1: y1[128,256] += z[16-row tile, 370-chunk] @ W1[chunk,256]
__global__ __launch_bounds__(256) void k_mlp1(const float* __restrict__ z,
    const float* __restrict__ W1, float* __restrict__ y1){
  __shared__ float zs[370 * 20];    // [j][r], row stride 20
  int rg = blockIdx.x;              // 0..7
  int kc = blockIdx.y;              // 0..63
  int b = rg >> 1;
  int t0 = (rg & 1) * 16;
  int base = kc * 370;
  int tid = threadIdx.x;
  for (int i = tid; i < 370 * 16; i += 256){
    int r = i / 370, j = i - r * 370;
    zs[j * 20 + r] = z[(size_t)(b * T_ + t0 + r) * NH_ + base + j];
  }
  __syncthreads();
  int cg = tid >> 6;
  int r0 = cg * 4;
  int c0 = (tid & 63) * 4;
  float4 acc0 = {0,0,0,0}, acc1 = {0,0,0,0}, acc2 = {0,0,0,0}, acc3 = {0,0,0,0};
  const float* wbase = W1 + (size_t)base * 256 + c0;
  #pragma unroll 2
  for (int j = 0; j < 370; ++j){
    float4 zv = *(const float4*)&zs[j * 20 + r0];
    float4 wv = *(const float4*)&wbase[(size_t)j * 256];
    acc0.x += zv.x * wv.x; acc0.y += zv.x * wv.y; acc0.z += zv.x * wv.z; acc0.w += zv.x * wv.w;
    acc1.x += zv.y * wv.x; acc1.y += zv.y * wv.y; acc1.z += zv.y * wv.z; acc1.w += zv.y * wv.w;
    acc2.x += zv.z * wv.x; acc2.y += zv.z * wv.y; acc2.z += zv.z * wv.z; acc2.w += zv.z * wv.w;
    acc3.x += zv.w * wv.x; acc3.y += zv.w * wv.y; acc3.z += zv.w * wv.z; acc3.w += zv.w * wv.w;
  }
  float4 av[4] = {acc0, acc1, acc2, acc3};
  #pragma unroll
  for (int rr = 0; rr < 4; ++rr){
    int row = b * T_ + t0 + r0 + rr;
    float* yp = &y1[(size_t)row * 256 + c0];
    atomicAdd(&yp[0], av[rr].x);
    atomicAdd(&yp[1], av[rr].y);
    atomicAdd(&yp[2], av[rr].z);
    atomicAdd(&yp[3], av[rr].w);
  }
}

// MLP layer 2: out[128,64] = gelu(y1+b1) @ W2 + b2
__global__ __launch_bounds__(64) void k_mlp2(const float* __restrict__ y1,
    const float* __restrict__ b1, const float* __restrict__ W2,
    const float* __restrict__ b2, float* __restrict__ outp){
  __shared__ float a[256];
  int row = blockIdx.x, tid = threadIdx.x;
  for (int i = tid; i < 256; i += 64) a[i] = gelu_f(y1[(size_t)row * 256 + i] + b1[i]);
  __syncthreads();
  float acc = b2[tid];
  for (int i = 0; i < 256; ++i) acc += a[i] * W2[i * 64 + tid];
  outp[row * 64 + tid] = acc;
}

extern "C" void kernel_launch(void* const* d_in, const int* in_sizes, int n_in,
                              void* d_out, int out_size, void* d_ws, size_t ws_size,
                              hipStream_t stream){
  const float* x     = (const float*)d_in[0];
  const int*   ei    = (const int*)  d_in[1];
  const float* ew    = (const float*)d_in[2];
  const float* W_gcn = (const float*)d_in[3];
  const float* b_gcn = (const float*)d_in[4];
  const float* W_gat = (const float*)d_in[5];
  const float* att_s = (const float*)d_in[6];
  const float* att_d = (const float*)d_in[7];
  const float* b_gat = (const float*)d_in[8];
  const float* W_t   = (const float*)d_in[9];
  const float* b_t   = (const float*)d_in[10];
  const float* ln_g  = (const float*)d_in[11];
  const float* ln_b  = (const float*)d_in[12];
  const float* W1    = (const float*)d_in[13];
  const float* b1    = (const float*)d_in[14];
  const float* W2    = (const float*)d_in[15];
  const float* b2    = (const float*)d_in[16];
  float* outp = (float*)d_out;

  float* F = (float*)d_ws;
  size_t off = 0;
  float* deg    = F + off; off += 512;
  float* gnorm  = F + off; off += 12288;
  float* csr_g  = F + off; off += 12288;
  float* asrc   = F + off; off += 189440;
  float* adst   = F + off; off += 189440;
  float* invden = F + off; off += 189440;
  float* y1     = F + off; off += 32768;
  float* h      = F + off; off += 3031040;
  float* bufB   = F + off; off += 3031040;   // hw / xt ping
  float* bufC   = F + off; off += 3031040;   // g / xt pong
  float* bufD   = F + off; off += 3031040;   // gh / z
  float* alpha  = F + off; off += (size_t)G_ * E2_ * 4;   // 6,251,520
  int* I        = (int*)(F + off);
  int* counts   = I;
  int* offs     = I + 512;
  int* cursor   = I + 1024;
  int* csr_soff = I + 1536;                  // E2_ entries

  hipMemsetAsync(deg, 0, 512 * sizeof(float), stream);
  hipMemsetAsync(counts, 0, 512 * sizeof(int), stream);
  hipMemsetAsync(y1, 0, 32768 * sizeof(float), stream);

  k_deg_count<<<48, 256, 0, stream>>>(ei, ew, deg, counts);
  k_gnorm<<<48, 256, 0, stream>>>(ei, ew, deg, gnorm);
  k_scan<<<1, 64, 0, stream>>>(counts, offs, cursor);
  k_fill<<<48, 256, 0, stream>>>(ei, gnorm, cursor, csr_soff, csr_g);
  hipMemcpyAsync(h, x, (size_t)GN_ * 64 * sizeof(float), hipMemcpyDeviceToDevice, stream);

  for (int l = 0; l < 3; ++l){
    k_rowgemm<<<1480, 256, 0, stream>>>(h, W_gcn + l * 4096, bufB);
    k_gcn_agg<<<11840, 256, 0, stream>>>(bufB, csr_soff, offs, csr_g, b_gcn + l * 64, bufC);
    k_rowgemm<<<1480, 256, 0, stream>>>(bufC, W_gat + l * 4096, bufD);
    k_attn<<<740, 256, 0, stream>>>(bufD, att_s + l * 64, att_d + l * 64, asrc, adst);
    k_alpha<<<740, 256, 0, stream>>>(asrc, adst, csr_soff, offs, alpha, invden);
    k_gat_agg<<<11840, 256, 0, stream>>>(bufD, alpha, invden, csr_soff, offs,
                                         b_gat + l * 64, ln_g + l * 64, ln_b + l * 64, h);
  }

  k_transpose2<<<BN_, 256, 0, stream>>>(h, bufB);
  k_tconv<<<BN_, 256, 0, stream>>>(bufB, W_t + 0 * 20480, b_t + 0 * 64, bufC);
  k_tconv<<<BN_, 256, 0, stream>>>(bufC, W_t + 1 * 20480, b_t + 1 * 64, bufB);
  k_tconv<<<BN_, 256, 0, stream>>>(bufB, W_t + 2 * 20480, b_t + 2 * 64, bufC);
  k_zshape<<<BN_, 256, 0, stream>>>(bufC, bufD);

  dim3 g1(8, 64);
  k_mlp1<<<g1, 256, 0, stream>>>(bufD, W1, y1);
  k_mlp2<<<128, 64, 0, stream>>>(y1, b1, W2, b2, outp);
}

// Round 5
// 922.481 us; speedup vs baseline: 1.6815x; 1.4650x over previous
//
#include <hip/hip_runtime.h>
#include <hip/hip_bf16.h>

// Problem constants
#define B_   4
#define T_   32
#define N_   370
#define E_   11840
#define E2_  12210          // E_ + N_ self loops
#define H_   64
#define G_   128            // B_*T_
#define GN_  47360          // G_*N_
#define BN_  1480           // B_*N_
#define NH_  23680          // N_*H_

__device__ __forceinline__ float gelu_f(float x){
  return 0.5f * x * (1.0f + erff(x * 0.7071067811865475f));
}
__device__ __forceinline__ float wsum64(float v){
  #pragma unroll
  for (int m = 32; m > 0; m >>= 1) v += __shfl_xor(v, m, 64);
  return v;
}
__device__ __forceinline__ float lrelu(float v){ return v > 0.f ? v : 0.2f * v; }

// ---------- edge preprocessing ----------
__global__ void k_deg_count(const int* __restrict__ ei, const float* __restrict__ ew,
                            float* __restrict__ deg, int* __restrict__ counts){
  int e = blockIdx.x * 256 + threadIdx.x;
  if (e >= E2_) return;
  int dst = (e < E_) ? ei[E_ + e] : (e - E_);
  float w = (e < E_) ? ew[e] : 1.0f;
  atomicAdd(&deg[dst], w);
  atomicAdd(&counts[dst], 1);
}

__global__ void k_gnorm(const int* __restrict__ ei, const float* __restrict__ ew,
                        const float* __restrict__ deg, float* __restrict__ gnorm){
  int e = blockIdx.x * 256 + threadIdx.x;
  if (e >= E2_) return;
  int s = (e < E_) ? ei[e] : (e - E_);
  int d = (e < E_) ? ei[E_ + e] : (e - E_);
  float w = (e < E_) ? ew[e] : 1.0f;
  float ds = deg[s] > 0.f ? rsqrtf(deg[s]) : 0.f;
  float dd = deg[d] > 0.f ? rsqrtf(deg[d]) : 0.f;
  gnorm[e] = ds * w * dd;
}

// wave-parallel exclusive scan over counts (one wave)
__global__ void k_scan(const int* __restrict__ counts, int* __restrict__ offs,
                       int* __restrict__ cursor){
  int lane = threadIdx.x;
  int run = 0;
  for (int c0 = 0; c0 < N_; c0 += 64){
    int n = c0 + lane;
    int v = (n < N_) ? counts[n] : 0;
    int s = v;
    #pragma unroll
    for (int m = 1; m < 64; m <<= 1){
      int t = __shfl_up(s, m, 64);
      if (lane >= m) s += t;
    }
    int excl = run + s - v;
    if (n < N_){ offs[n] = excl; cursor[n] = excl; }
    run += __shfl(s, 63, 64);
  }
  if (lane == 0) offs[N_] = run;
}

// stores PRE-SCALED source offset s*64 (element offset of row start)
__global__ void k_fill(const int* __restrict__ ei, const float* __restrict__ gnorm,
                       int* __restrict__ cursor, int* __restrict__ csr_soff,
                       float* __restrict__ csr_g){
  int e = blockIdx.x * 256 + threadIdx.x;
  if (e >= E2_) return;
  int s = (e < E_) ? ei[e] : (e - E_);
  int d = (e < E_) ? ei[E_ + e] : (e - E_);
  int pos = atomicAdd(&cursor[d], 1);
  csr_soff[pos] = s * 64;
  csr_g[pos] = gnorm[e];
}

// rows x 64 @ 64 x 64 -> rows x 64 ; 32 rows/block, 4x2 register tile
__global__ __launch_bounds__(256) void k_rowgemm(const float* __restrict__ in,
                                                 const float* __restrict__ W,
                                                 float* __restrict__ outp){
  __shared__ float Ws[64 * 64];     // [k][col]
  __shared__ float rsT[64 * 36];    // [k][row], padded to 36
  int tid = threadIdx.x;
  size_t r0 = (size_t)blockIdx.x * 32;
  for (int i = tid; i < 4096; i += 256) Ws[i] = W[i];
  for (int i = tid; i < 2048; i += 256){
    int r = i >> 6, k = i & 63;
    rsT[k * 36 + r] = in[(r0 + r) * 64 + k];
  }
  __syncthreads();
  int cp = tid & 31;       // col pair id
  int rg = tid >> 5;       // row group 0..7 (4 rows each)
  int c0 = cp * 2;
  int rr0 = rg * 4;
  float2 acc0 = {0.f,0.f}, acc1 = {0.f,0.f}, acc2 = {0.f,0.f}, acc3 = {0.f,0.f};
  #pragma unroll 4
  for (int k = 0; k < 64; ++k){
    float4 rv = *(const float4*)&rsT[k * 36 + rr0];
    float2 wv = *(const float2*)&Ws[k * 64 + c0];
    acc0.x += rv.x * wv.x; acc0.y += rv.x * wv.y;
    acc1.x += rv.y * wv.x; acc1.y += rv.y * wv.y;
    acc2.x += rv.z * wv.x; acc2.y += rv.z * wv.y;
    acc3.x += rv.w * wv.x; acc3.y += rv.w * wv.y;
  }
  *(float2*)&outp[(r0 + rr0 + 0) * 64 + c0] = acc0;
  *(float2*)&outp[(r0 + rr0 + 1) * 64 + c0] = acc1;
  *(float2*)&outp[(r0 + rr0 + 2) * 64 + c0] = acc2;
  *(float2*)&outp[(r0 + rr0 + 3) * 64 + c0] = acc3;
}

// GCN aggregate: 4 (g,n) per block, one wave each; edge loop unrolled x8 for MLP
__global__ __launch_bounds__(256) void k_gcn_agg(const float* __restrict__ hw,
    const int* __restrict__ csr_soff, const int* __restrict__ offs,
    const float* __restrict__ csr_g, const float* __restrict__ b_gcn,
    float* __restrict__ gout){
  int gn = blockIdx.x * 4 + (threadIdx.x >> 6);
  int c = threadIdx.x & 63;
  int g = gn / N_, n = gn - g * N_;
  int o0 = offs[n], o1 = offs[n + 1];
  const float* hwg = hw + (size_t)g * (N_ * 64);
  float acc = 0.f;
  int p = o0;
  for (; p + 8 <= o1; p += 8){
    int s0 = csr_soff[p+0], s1 = csr_soff[p+1], s2 = csr_soff[p+2], s3 = csr_soff[p+3];
    int s4 = csr_soff[p+4], s5 = csr_soff[p+5], s6 = csr_soff[p+6], s7 = csr_soff[p+7];
    float w0 = csr_g[p+0], w1 = csr_g[p+1], w2 = csr_g[p+2], w3 = csr_g[p+3];
    float w4 = csr_g[p+4], w5 = csr_g[p+5], w6 = csr_g[p+6], w7 = csr_g[p+7];
    float v0 = hwg[s0+c], v1 = hwg[s1+c], v2 = hwg[s2+c], v3 = hwg[s3+c];
    float v4 = hwg[s4+c], v5 = hwg[s5+c], v6 = hwg[s6+c], v7 = hwg[s7+c];
    acc += w0*v0 + w1*v1 + w2*v2 + w3*v3 + w4*v4 + w5*v5 + w6*v6 + w7*v7;
  }
  for (; p < o1; ++p)
    acc += csr_g[p] * hwg[csr_soff[p] + c];
  acc += b_gcn[c];
  gout[(size_t)gn * 64 + c] = gelu_f(acc);
}

// attention scores per (g,n,head)
__global__ void k_attn(const float* __restrict__ gh, const float* __restrict__ att_s,
                       const float* __restrict__ att_d, float* __restrict__ asrc,
                       float* __restrict__ adst){
  int idx = blockIdx.x * 256 + threadIdx.x;   // GN_*4 exact
  int head = idx & 3;
  int gn = idx >> 2;
  const float* row = gh + (size_t)gn * 64 + head * 16;
  float as = 0.f, ad = 0.f;
  #pragma unroll
  for (int d = 0; d < 16; ++d){
    float v = row[d];
    as += v * att_s[head * 16 + d];
    ad += v * att_d[head * 16 + d];
  }
  asrc[idx] = as;
  adst[idx] = ad;
}

// per (g,n,head): softmax max+denominator over incoming edges;
// writes UNNORMALIZED exp weights alpha[g][p][head] and invden[g][n][head]
__global__ void k_alpha(const float* __restrict__ asrc, const float* __restrict__ adst,
                        const int* __restrict__ csr_soff, const int* __restrict__ offs,
                        float* __restrict__ alpha, float* __restrict__ invden){
  int idx = blockIdx.x * 256 + threadIdx.x;   // (g*N+n)*4+head, GN_*4 exact
  int head = idx & 3;
  int gn = idx >> 2;
  int g = gn / N_, n = gn - g * N_;
  int o0 = offs[n], o1 = offs[n + 1];
  const float* as_g = asrc + (size_t)g * (N_ * 4);
  float adv = adst[idx];
  float m = -1e30f;
  int p = o0;
  for (; p + 4 <= o1; p += 4){
    int sa = csr_soff[p+0] >> 4, sb = csr_soff[p+1] >> 4;
    int sc = csr_soff[p+2] >> 4, sd = csr_soff[p+3] >> 4;
    float va = lrelu(as_g[sa + head] + adv);
    float vb = lrelu(as_g[sb + head] + adv);
    float vc = lrelu(as_g[sc + head] + adv);
    float vd = lrelu(as_g[sd + head] + adv);
    m = fmaxf(m, fmaxf(fmaxf(va, vb), fmaxf(vc, vd)));
  }
  for (; p < o1; ++p)
    m = fmaxf(m, lrelu(as_g[(csr_soff[p] >> 4) + head] + adv));
  float* al_g = alpha + (size_t)g * (E2_ * 4);
  float den = 0.f;
  p = o0;
  for (; p + 4 <= o1; p += 4){
    int sa = csr_soff[p+0] >> 4, sb = csr_soff[p+1] >> 4;
    int sc = csr_soff[p+2] >> 4, sd = csr_soff[p+3] >> 4;
    float ea = __expf(lrelu(as_g[sa + head] + adv) - m);
    float eb = __expf(lrelu(as_g[sb + head] + adv) - m);
    float ec = __expf(lrelu(as_g[sc + head] + adv) - m);
    float ed = __expf(lrelu(as_g[sd + head] + adv) - m);
    den += ea + eb + ec + ed;
    al_g[(p+0)*4 + head] = ea;
    al_g[(p+1)*4 + head] = eb;
    al_g[(p+2)*4 + head] = ec;
    al_g[(p+3)*4 + head] = ed;
  }
  for (; p < o1; ++p){
    float ex = __expf(lrelu(as_g[(csr_soff[p] >> 4) + head] + adv) - m);
    den += ex;
    al_g[p*4 + head] = ex;
  }
  invden[idx] = 1.f / den;
}

// GAT aggregate (single pass, precomputed alpha) + bias + residual + LayerNorm
__global__ __launch_bounds__(256) void k_gat_agg(const float* __restrict__ gh,
    const float* __restrict__ alpha, const float* __restrict__ invden,
    const int* __restrict__ csr_soff, const int* __restrict__ offs,
    const float* __restrict__ b_gat, const float* __restrict__ ln_g,
    const float* __restrict__ ln_b, float* __restrict__ h){
  int gn = blockIdx.x * 4 + (threadIdx.x >> 6);
  int c = threadIdx.x & 63;
  int g = gn / N_, n = gn - g * N_;
  int head = c >> 4;
  int o0 = offs[n], o1 = offs[n + 1];
  const float* gh_g = gh + (size_t)g * (N_ * 64);
  const float* al_g = alpha + (size_t)g * (E2_ * 4);
  size_t hidx = (size_t)gn * 64 + c;
  float hres = h[hidx];
  float acc = 0.f;
  int p = o0;
  for (; p + 8 <= o1; p += 8){
    int s0 = csr_soff[p+0], s1 = csr_soff[p+1], s2 = csr_soff[p+2], s3 = csr_soff[p+3];
    int s4 = csr_soff[p+4], s5 = csr_soff[p+5], s6 = csr_soff[p+6], s7 = csr_soff[p+7];
    float a0 = al_g[(p+0)*4+head], a1 = al_g[(p+1)*4+head];
    float a2 = al_g[(p+2)*4+head], a3 = al_g[(p+3)*4+head];
    float a4 = al_g[(p+4)*4+head], a5 = al_g[(p+5)*4+head];
    float a6 = al_g[(p+6)*4+head], a7 = al_g[(p+7)*4+head];
    float v0 = gh_g[s0+c], v1 = gh_g[s1+c], v2 = gh_g[s2+c], v3 = gh_g[s3+c];
    float v4 = gh_g[s4+c], v5 = gh_g[s5+c], v6 = gh_g[s6+c], v7 = gh_g[s7+c];
    acc += a0*v0 + a1*v1 + a2*v2 + a3*v3 + a4*v4 + a5*v5 + a6*v6 + a7*v7;
  }
  for (; p < o1; ++p)
    acc += al_g[p*4+head] * gh_g[csr_soff[p] + c];
  float outv = acc * invden[gn * 4 + head] + b_gat[c];
  float r = outv + hres;
  float mu = wsum64(r) * (1.f / 64.f);
  float d = r - mu;
  float var = wsum64(d * d) * (1.f / 64.f);
  h[hidx] = d * rsqrtf(var + 1e-5f) * ln_g[c] + ln_b[c];
}

// (B,T,N,H) -> (B*N, H, T) via LDS tile; one block per (b,n)
__global__ __launch_bounds__(256) void k_transpose2(const float* __restrict__ h,
                                                    float* __restrict__ xt){
  __shared__ float tile[64 * 33];
  int bn = blockIdx.x;
  int b = bn / N_, n = bn - b * N_;
  int tid = threadIdx.x;
  for (int i = tid; i < 2048; i += 256){
    int t = i >> 6, ch = i & 63;
    tile[ch * 33 + t] = h[((size_t)(b * T_ + t) * N_ + n) * 64 + ch];
  }
  __syncthreads();
  size_t base = (size_t)bn * 2048;
  for (int i = tid; i < 2048; i += 256){
    int ho = i >> 5, t = i & 31;
    xt[base + i] = tile[ho * 33 + t];
  }
}

// temporal conv layer: out = gelu(conv(x)+b)+x ; one block per (b,n)
__global__ __launch_bounds__(256) void k_tconv(const float* __restrict__ xin_g,
    const float* __restrict__ Wt, const float* __restrict__ bt,
    float* __restrict__ xout_g){
  __shared__ float xs2[64 * 36];
  __shared__ float WsT[320 * 65];
  int bn = blockIdx.x;
  size_t base = (size_t)bn * 2048;
  int tid = threadIdx.x;
  for (int i = tid; i < 64 * 36; i += 256) xs2[i] = 0.f;
  for (int i = tid; i < 20480; i += 256){
    int ho = i / 320, j = i - ho * 320;
    WsT[j * 65 + ho] = Wt[i];
  }
  __syncthreads();
  for (int i = tid; i < 2048; i += 256){
    int ci = i >> 5, t = i & 31;
    xs2[ci * 36 + 2 + t] = xin_g[base + i];
  }
  __syncthreads();
  int tq = tid >> 6;        // wave id -> t block of 8
  int ho = tid & 63;
  int t0 = tq * 8;
  float bv = bt[ho];
  float acc[8];
  #pragma unroll
  for (int r = 0; r < 8; ++r) acc[r] = bv;
  for (int ci = 0; ci < 64; ++ci){
    const float* xr = &xs2[ci * 36 + t0];   // xr[q] = x[ci][t0+q-2]
    float4 xa = *(const float4*)&xr[0];
    float4 xb = *(const float4*)&xr[4];
    float4 xc = *(const float4*)&xr[8];
    float xw[12] = {xa.x, xa.y, xa.z, xa.w, xb.x, xb.y, xb.z, xb.w,
                    xc.x, xc.y, xc.z, xc.w};
    const float* wr = &WsT[(ci * 5) * 65 + ho];
    #pragma unroll
    for (int k = 0; k < 5; ++k){
      float w = wr[k * 65];
      #pragma unroll
      for (int r = 0; r < 8; ++r) acc[r] += xw[r + k] * w;
    }
  }
  #pragma unroll
  for (int r = 0; r < 8; ++r){
    int t = t0 + r;
    xout_g[base + ho * 32 + t] = gelu_f(acc[r]) + xs2[ho * 36 + 2 + t];
  }
}

// (B*N, H, T) -> z[(b*T+t)][N*H] via LDS tile
__global__ __launch_bounds__(256) void k_zshape(const float* __restrict__ xt,
                                                float* __restrict__ z){
  __shared__ float tile[64 * 33];
  int bn = blockIdx.x;
  int b = bn / N_, n = bn - b * N_;
  int tid = threadIdx.x;
  size_t base = (size_t)bn * 2048;
  for (int i = tid; i < 2048; i += 256){
    int ho = i >> 5, t = i & 31;
    tile[ho * 33 + t] = xt[base + i];
  }
  __syncthreads();
  for (int i = tid; i < 2048; i += 256){
    int t = i >> 6, ch = i & 63;
    z[(size_t)(b * T_ + t) * NH_ + n * 64 + ch] = tile[ch * 33 + t];
  }
}

// MLP layer 1: y1[128,256] += z[16-row tile, 370-chunk] @ W1[chunk,256]
__global__ __launch_bounds__(256) void k_mlp1(const float* __restrict__ z,
    const float* __restrict__ W1, float* __restrict__ y1){
  __shared__ float zs[370 * 20];    // [j][r], row stride 20
  int rg = blockIdx.x;              // 0..7
  int kc = blockIdx.y;              // 0..63
  int b = rg >> 1;
  int t0 = (rg & 1) * 16;
  int base = kc * 370;
  int tid = threadIdx.x;
  for (int i = tid; i < 370 * 16; i += 256){
    int r = i / 370, j = i - r * 370;
    zs[j * 20 + r] = z[(size_t)(b * T_ + t0 + r) * NH_ + base + j];
  }
  __syncthreads();
  int cg = tid >> 6;
  int r0 = cg * 4;
  int c0 = (tid & 63) * 4;
  float4 acc0 = {0,0,0,0}, acc1 = {0,0,0,0}, acc2 = {0,0,0,0}, acc3 = {0,0,0,0};
  const float* wbase = W1 + (size_t)base * 256 + c0;
  #pragma unroll 2
  for (int j = 0; j < 370; ++j){
    float4 zv = *(const float4*)&zs[j * 20 + r0];
    float4 wv = *(const float4*)&wbase[(size_t)j * 256];
    acc0.x += zv.x * wv.x; acc0.y += zv.x * wv.y; acc0.z += zv.x * wv.z; acc0.w += zv.x * wv.w;
    acc1.x += zv.y * wv.x; acc1.y += zv.y * wv.y; acc1.z += zv.y * wv.z; acc1.w += zv.y * wv.w;
    acc2.x += zv.z * wv.x; acc2.y += zv.z * wv.y; acc2.z += zv.z * wv.z; acc2.w += zv.z * wv.w;
    acc3.x += zv.w * wv.x; acc3.y += zv.w * wv.y; acc3.z += zv.w * wv.z; acc3.w += zv.w * wv.w;
  }
  float4 av[4] = {acc0, acc1, acc2, acc3};
  #pragma unroll
  for (int rr = 0; rr < 4; ++rr){
    int row = b * T_ + t0 + r0 + rr;
    float* yp = &y1[(size_t)row * 256 + c0];
    atomicAdd(&yp[0], av[rr].x);
    atomicAdd(&yp[1], av[rr].y);
    atomicAdd(&yp[2], av[rr].z);
    atomicAdd(&yp[3], av[rr].w);
  }
}

// MLP layer 2: out[128,64] = gelu(y1+b1) @ W2 + b2
__global__ __launch_bounds__(64) void k_mlp2(const float* __restrict__ y1,
    const float* __restrict__ b1, const float* __restrict__ W2,
    const float* __restrict__ b2, float* __restrict__ outp){
  __shared__ float a[256];
  int row = blockIdx.x, tid = threadIdx.x;
  for (int i = tid; i < 256; i += 64) a[i] = gelu_f(y1[(size_t)row * 256 + i] + b1[i]);
  __syncthreads();
  float acc = b2[tid];
  for (int i = 0; i < 256; ++i) acc += a[i] * W2[i * 64 + tid];
  outp[row * 64 + tid] = acc;
}

extern "C" void kernel_launch(void* const* d_in, const int* in_sizes, int n_in,
                              void* d_out, int out_size, void* d_ws, size_t ws_size,
                              hipStream_t stream){
  const float* x     = (const float*)d_in[0];
  const int*   ei    = (const int*)  d_in[1];
  const float* ew    = (const float*)d_in[2];
  const float* W_gcn = (const float*)d_in[3];
  const float* b_gcn = (const float*)d_in[4];
  const float* W_gat = (const float*)d_in[5];
  const float* att_s = (const float*)d_in[6];
  const float* att_d = (const float*)d_in[7];
  const float* b_gat = (const float*)d_in[8];
  const float* W_t   = (const float*)d_in[9];
  const float* b_t   = (const float*)d_in[10];
  const float* ln_g  = (const float*)d_in[11];
  const float* ln_b  = (const float*)d_in[12];
  const float* W1    = (const float*)d_in[13];
  const float* b1    = (const float*)d_in[14];
  const float* W2    = (const float*)d_in[15];
  const float* b2    = (const float*)d_in[16];
  float* outp = (float*)d_out;

  float* F = (float*)d_ws;
  size_t off = 0;
  float* deg    = F + off; off += 512;
  float* gnorm  = F + off; off += 12288;
  float* csr_g  = F + off; off += 12288;
  float* asrc   = F + off; off += 189440;
  float* adst   = F + off; off += 189440;
  float* invden = F + off; off += 189440;
  float* y1     = F + off; off += 32768;
  float* h      = F + off; off += 3031040;
  float* bufB   = F + off; off += 3031040;   // hw / xt ping
  float* bufC   = F + off; off += 3031040;   // g / xt pong
  float* bufD   = F + off; off += 3031040;   // gh / z
  float* alpha  = F + off; off += (size_t)G_ * E2_ * 4;   // 6,251,520
  int* I        = (int*)(F + off);
  int* counts   = I;
  int* offs     = I + 512;
  int* cursor   = I + 1024;
  int* csr_soff = I + 1536;                  // E2_ entries

  hipMemsetAsync(deg, 0, 512 * sizeof(float), stream);
  hipMemsetAsync(counts, 0, 512 * sizeof(int), stream);
  hipMemsetAsync(y1, 0, 32768 * sizeof(float), stream);

  k_deg_count<<<48, 256, 0, stream>>>(ei, ew, deg, counts);
  k_gnorm<<<48, 256, 0, stream>>>(ei, ew, deg, gnorm);
  k_scan<<<1, 64, 0, stream>>>(counts, offs, cursor);
  k_fill<<<48, 256, 0, stream>>>(ei, gnorm, cursor, csr_soff, csr_g);
  hipMemcpyAsync(h, x, (size_t)GN_ * 64 * sizeof(float), hipMemcpyDeviceToDevice, stream);

  for (int l = 0; l < 3; ++l){
    k_rowgemm<<<1480, 256, 0, stream>>>(h, W_gcn + l * 4096, bufB);
    k_gcn_agg<<<11840, 256, 0, stream>>>(bufB, csr_soff, offs, csr_g, b_gcn + l * 64, bufC);
    k_rowgemm<<<1480, 256, 0, stream>>>(bufC, W_gat + l * 4096, bufD);
    k_attn<<<740, 256, 0, stream>>>(bufD, att_s + l * 64, att_d + l * 64, asrc, adst);
    k_alpha<<<740, 256, 0, stream>>>(asrc, adst, csr_soff, offs, alpha, invden);
    k_gat_agg<<<11840, 256, 0, stream>>>(bufD, alpha, invden, csr_soff, offs,
                                         b_gat + l * 64, ln_g + l * 64, ln_b + l * 64, h);
  }

  k_transpose2<<<BN_, 256, 0, stream>>>(h, bufB);
  k_tconv<<<BN_, 256, 0, stream>>>(bufB, W_t + 0 * 20480, b_t + 0 * 64, bufC);
  k_tconv<<<BN_, 256, 0, stream>>>(bufC, W_t + 1 * 20480, b_t + 1 * 64, bufB);
  k_tconv<<<BN_, 256, 0, stream>>>(bufB, W_t + 2 * 20480, b_t + 2 * 64, bufC);
  k_zshape<<<BN_, 256, 0, stream>>>(bufC, bufD);

  dim3 g1(8, 64);
  k_mlp1<<<g1, 256, 0, stream>>>(bufD, W1, y1);
  k_mlp2<<<128, 64, 0, stream>>>(y1, b1, W2, b2, outp);
}

// Round 6
// 762.066 us; speedup vs baseline: 2.0355x; 1.2105x over previous
//
#include <hip/hip_runtime.h>
#include <hip/hip_bf16.h>

// Problem constants
#define B_   4
#define T_   32
#define N_   370
#define E_   11840
#define E2_  12210          // E_ + N_ self loops
#define H_   64
#define G_   128            // B_*T_
#define GN_  47360          // G_*N_
#define BN_  1480           // B_*N_
#define NH_  23680          // N_*H_

__device__ __forceinline__ float gelu_f(float x){
  return 0.5f * x * (1.0f + erff(x * 0.7071067811865475f));
}
__device__ __forceinline__ float wsum64(float v){
  #pragma unroll
  for (int m = 32; m > 0; m >>= 1) v += __shfl_xor(v, m, 64);
  return v;
}
__device__ __forceinline__ float lrelu(float v){ return v > 0.f ? v : 0.2f * v; }

// ---------- edge preprocessing ----------
__global__ void k_deg_count(const int* __restrict__ ei, const float* __restrict__ ew,
                            float* __restrict__ deg, int* __restrict__ counts){
  int e = blockIdx.x * 256 + threadIdx.x;
  if (e >= E2_) return;
  int dst = (e < E_) ? ei[E_ + e] : (e - E_);
  float w = (e < E_) ? ew[e] : 1.0f;
  atomicAdd(&deg[dst], w);
  atomicAdd(&counts[dst], 1);
}

__global__ void k_gnorm(const int* __restrict__ ei, const float* __restrict__ ew,
                        const float* __restrict__ deg, float* __restrict__ gnorm){
  int e = blockIdx.x * 256 + threadIdx.x;
  if (e >= E2_) return;
  int s = (e < E_) ? ei[e] : (e - E_);
  int d = (e < E_) ? ei[E_ + e] : (e - E_);
  float w = (e < E_) ? ew[e] : 1.0f;
  float ds = deg[s] > 0.f ? rsqrtf(deg[s]) : 0.f;
  float dd = deg[d] > 0.f ? rsqrtf(deg[d]) : 0.f;
  gnorm[e] = ds * w * dd;
}

// wave-parallel exclusive scan over counts (one wave)
__global__ void k_scan(const int* __restrict__ counts, int* __restrict__ offs,
                       int* __restrict__ cursor){
  int lane = threadIdx.x;
  int run = 0;
  for (int c0 = 0; c0 < N_; c0 += 64){
    int n = c0 + lane;
    int v = (n < N_) ? counts[n] : 0;
    int s = v;
    #pragma unroll
    for (int m = 1; m < 64; m <<= 1){
      int t = __shfl_up(s, m, 64);
      if (lane >= m) s += t;
    }
    int excl = run + s - v;
    if (n < N_){ offs[n] = excl; cursor[n] = excl; }
    run += __shfl(s, 63, 64);
  }
  if (lane == 0) offs[N_] = run;
}

// stores PRE-SCALED source offset s*64 (element offset of row start)
__global__ void k_fill(const int* __restrict__ ei, const float* __restrict__ gnorm,
                       int* __restrict__ cursor, int* __restrict__ csr_soff,
                       float* __restrict__ csr_g){
  int e = blockIdx.x * 256 + threadIdx.x;
  if (e >= E2_) return;
  int s = (e < E_) ? ei[e] : (e - E_);
  int d = (e < E_) ? ei[E_ + e] : (e - E_);
  int pos = atomicAdd(&cursor[d], 1);
  csr_soff[pos] = s * 64;
  csr_g[pos] = gnorm[e];
}

// transpose temporal-conv weights: WT[l][(ci*5+k)*64 + ho] = W_t[l][ho*320+ci*5+k]
__global__ void k_wtr(const float* __restrict__ Wt, float* __restrict__ WT){
  int i = blockIdx.x * 256 + threadIdx.x;     // 3*20480 exact
  int l = i / 20480, rem = i - l * 20480;
  int ho = rem / 320, j = rem - ho * 320;
  WT[l * 20480 + j * 64 + ho] = Wt[i];
}

// rows x 64 @ 64 x 64 -> rows x 64 ; 64 rows/block, 4x4 register tile
__global__ __launch_bounds__(256) void k_rowgemm(const float* __restrict__ in,
                                                 const float* __restrict__ W,
                                                 float* __restrict__ outp){
  __shared__ float Ws[64 * 64];     // [k][col]
  __shared__ float rsT[64 * 68];    // [k][row], padded
  int tid = threadIdx.x;
  size_t r0 = (size_t)blockIdx.x * 64;
  for (int i = tid; i < 4096; i += 256) Ws[i] = W[i];
  for (int i = tid; i < 4096; i += 256){
    int r = i >> 6, k = i & 63;
    rsT[k * 68 + r] = in[(r0 + r) * 64 + k];
  }
  __syncthreads();
  int c0 = (tid & 15) * 4;
  int rr0 = (tid >> 4) * 4;
  float4 a0 = {0,0,0,0}, a1 = {0,0,0,0}, a2 = {0,0,0,0}, a3 = {0,0,0,0};
  #pragma unroll 4
  for (int k = 0; k < 64; ++k){
    float4 rv = *(const float4*)&rsT[k * 68 + rr0];
    float4 wv = *(const float4*)&Ws[k * 64 + c0];
    a0.x += rv.x*wv.x; a0.y += rv.x*wv.y; a0.z += rv.x*wv.z; a0.w += rv.x*wv.w;
    a1.x += rv.y*wv.x; a1.y += rv.y*wv.y; a1.z += rv.y*wv.z; a1.w += rv.y*wv.w;
    a2.x += rv.z*wv.x; a2.y += rv.z*wv.y; a2.z += rv.z*wv.z; a2.w += rv.z*wv.w;
    a3.x += rv.w*wv.x; a3.y += rv.w*wv.y; a3.z += rv.w*wv.z; a3.w += rv.w*wv.w;
  }
  *(float4*)&outp[(r0 + rr0 + 0) * 64 + c0] = a0;
  *(float4*)&outp[(r0 + rr0 + 1) * 64 + c0] = a1;
  *(float4*)&outp[(r0 + rr0 + 2) * 64 + c0] = a2;
  *(float4*)&outp[(r0 + rr0 + 3) * 64 + c0] = a3;
}

// GCN aggregate: 4 (g,n) per block, one wave each; edge loop unrolled x8 for MLP
__global__ __launch_bounds__(256) void k_gcn_agg(const float* __restrict__ hw,
    const int* __restrict__ csr_soff, const int* __restrict__ offs,
    const float* __restrict__ csr_g, const float* __restrict__ b_gcn,
    float* __restrict__ gout){
  int gn = blockIdx.x * 4 + (threadIdx.x >> 6);
  int c = threadIdx.x & 63;
  int g = gn / N_, n = gn - g * N_;
  int o0 = offs[n], o1 = offs[n + 1];
  const float* hwg = hw + (size_t)g * (N_ * 64);
  float acc = 0.f;
  int p = o0;
  for (; p + 8 <= o1; p += 8){
    int s0 = csr_soff[p+0], s1 = csr_soff[p+1], s2 = csr_soff[p+2], s3 = csr_soff[p+3];
    int s4 = csr_soff[p+4], s5 = csr_soff[p+5], s6 = csr_soff[p+6], s7 = csr_soff[p+7];
    float w0 = csr_g[p+0], w1 = csr_g[p+1], w2 = csr_g[p+2], w3 = csr_g[p+3];
    float w4 = csr_g[p+4], w5 = csr_g[p+5], w6 = csr_g[p+6], w7 = csr_g[p+7];
    float v0 = hwg[s0+c], v1 = hwg[s1+c], v2 = hwg[s2+c], v3 = hwg[s3+c];
    float v4 = hwg[s4+c], v5 = hwg[s5+c], v6 = hwg[s6+c], v7 = hwg[s7+c];
    acc += w0*v0 + w1*v1 + w2*v2 + w3*v3 + w4*v4 + w5*v5 + w6*v6 + w7*v7;
  }
  for (; p < o1; ++p)
    acc += csr_g[p] * hwg[csr_soff[p] + c];
  acc += b_gcn[c];
  gout[(size_t)gn * 64 + c] = gelu_f(acc);
}

// attention scores per (g,n,head)
__global__ void k_attn(const float* __restrict__ gh, const float* __restrict__ att_s,
                       const float* __restrict__ att_d, float* __restrict__ asrc,
                       float* __restrict__ adst){
  int idx = blockIdx.x * 256 + threadIdx.x;   // GN_*4 exact
  int head = idx & 3;
  int gn = idx >> 2;
  const float* row = gh + (size_t)gn * 64 + head * 16;
  float as = 0.f, ad = 0.f;
  #pragma unroll
  for (int d = 0; d < 16; ++d){
    float v = row[d];
    as += v * att_s[head * 16 + d];
    ad += v * att_d[head * 16 + d];
  }
  asrc[idx] = as;
  adst[idx] = ad;
}

// per (g,n,head): softmax max+denominator over incoming edges;
// writes UNNORMALIZED exp weights alpha[g][p][head] and invden[g][n][head]
__global__ void k_alpha(const float* __restrict__ asrc, const float* __restrict__ adst,
                        const int* __restrict__ csr_soff, const int* __restrict__ offs,
                        float* __restrict__ alpha, float* __restrict__ invden){
  int idx = blockIdx.x * 256 + threadIdx.x;   // (g*N+n)*4+head, GN_*4 exact
  int head = idx & 3;
  int gn = idx >> 2;
  int g = gn / N_, n = gn - g * N_;
  int o0 = offs[n], o1 = offs[n + 1];
  const float* as_g = asrc + (size_t)g * (N_ * 4);
  float adv = adst[idx];
  float m = -1e30f;
  int p = o0;
  for (; p + 4 <= o1; p += 4){
    int sa = csr_soff[p+0] >> 4, sb = csr_soff[p+1] >> 4;
    int sc = csr_soff[p+2] >> 4, sd = csr_soff[p+3] >> 4;
    float va = lrelu(as_g[sa + head] + adv);
    float vb = lrelu(as_g[sb + head] + adv);
    float vc = lrelu(as_g[sc + head] + adv);
    float vd = lrelu(as_g[sd + head] + adv);
    m = fmaxf(m, fmaxf(fmaxf(va, vb), fmaxf(vc, vd)));
  }
  for (; p < o1; ++p)
    m = fmaxf(m, lrelu(as_g[(csr_soff[p] >> 4) + head] + adv));
  float* al_g = alpha + (size_t)g * (E2_ * 4);
  float den = 0.f;
  p = o0;
  for (; p + 4 <= o1; p += 4){
    int sa = csr_soff[p+0] >> 4, sb = csr_soff[p+1] >> 4;
    int sc = csr_soff[p+2] >> 4, sd = csr_soff[p+3] >> 4;
    float ea = __expf(lrelu(as_g[sa + head] + adv) - m);
    float eb = __expf(lrelu(as_g[sb + head] + adv) - m);
    float ec = __expf(lrelu(as_g[sc + head] + adv) - m);
    float ed = __expf(lrelu(as_g[sd + head] + adv) - m);
    den += ea + eb + ec + ed;
    al_g[(p+0)*4 + head] = ea;
    al_g[(p+1)*4 + head] = eb;
    al_g[(p+2)*4 + head] = ec;
    al_g[(p+3)*4 + head] = ed;
  }
  for (; p < o1; ++p){
    float ex = __expf(lrelu(as_g[(csr_soff[p] >> 4) + head] + adv) - m);
    den += ex;
    al_g[p*4 + head] = ex;
  }
  invden[idx] = 1.f / den;
}

// GAT aggregate (single pass, precomputed alpha) + bias + residual + LayerNorm
__global__ __launch_bounds__(256) void k_gat_agg(const float* __restrict__ gh,
    const float* __restrict__ alpha, const float* __restrict__ invden,
    const int* __restrict__ csr_soff, const int* __restrict__ offs,
    const float* __restrict__ b_gat, const float* __restrict__ ln_g,
    const float* __restrict__ ln_b, float* __restrict__ h){
  int gn = blockIdx.x * 4 + (threadIdx.x >> 6);
  int c = threadIdx.x & 63;
  int g = gn / N_, n = gn - g * N_;
  int head = c >> 4;
  int o0 = offs[n], o1 = offs[n + 1];
  const float* gh_g = gh + (size_t)g * (N_ * 64);
  const float* al_g = alpha + (size_t)g * (E2_ * 4);
  size_t hidx = (size_t)gn * 64 + c;
  float hres = h[hidx];
  float acc = 0.f;
  int p = o0;
  for (; p + 8 <= o1; p += 8){
    int s0 = csr_soff[p+0], s1 = csr_soff[p+1], s2 = csr_soff[p+2], s3 = csr_soff[p+3];
    int s4 = csr_soff[p+4], s5 = csr_soff[p+5], s6 = csr_soff[p+6], s7 = csr_soff[p+7];
    float a0 = al_g[(p+0)*4+head], a1 = al_g[(p+1)*4+head];
    float a2 = al_g[(p+2)*4+head], a3 = al_g[(p+3)*4+head];
    float a4 = al_g[(p+4)*4+head], a5 = al_g[(p+5)*4+head];
    float a6 = al_g[(p+6)*4+head], a7 = al_g[(p+7)*4+head];
    float v0 = gh_g[s0+c], v1 = gh_g[s1+c], v2 = gh_g[s2+c], v3 = gh_g[s3+c];
    float v4 = gh_g[s4+c], v5 = gh_g[s5+c], v6 = gh_g[s6+c], v7 = gh_g[s7+c];
    acc += a0*v0 + a1*v1 + a2*v2 + a3*v3 + a4*v4 + a5*v5 + a6*v6 + a7*v7;
  }
  for (; p < o1; ++p)
    acc += al_g[p*4+head] * gh_g[csr_soff[p] + c];
  float outv = acc * invden[gn * 4 + head] + b_gat[c];
  float r = outv + hres;
  float mu = wsum64(r) * (1.f / 64.f);
  float d = r - mu;
  float var = wsum64(d * d) * (1.f / 64.f);
  h[hidx] = d * rsqrtf(var + 1e-5f) * ln_g[c] + ln_b[c];
}

// Fused: transpose + 3 temporal conv layers + reshape to z. One block per (b,n).
// x tiles [64][36] ping/pong in LDS (pad 2 each side of t); W read from global
// in transposed [ci*5+k][ho] layout (coalesced 256B, L2-resident).
__global__ __launch_bounds__(256) void k_tfuse(const float* __restrict__ h,
    const float* __restrict__ WT, const float* __restrict__ bt,
    float* __restrict__ z){
  __shared__ float xa[64 * 36];
  __shared__ float xb[64 * 36];
  int bn = blockIdx.x;
  int b = bn / N_, n = bn - b * N_;
  int tid = threadIdx.x;
  for (int i = tid; i < 64 * 36; i += 256){ xa[i] = 0.f; xb[i] = 0.f; }
  __syncthreads();
  for (int i = tid; i < 2048; i += 256){
    int t = i >> 6, ch = i & 63;
    xa[ch * 36 + 2 + t] = h[((size_t)(b * T_ + t) * N_ + n) * 64 + ch];
  }
  __syncthreads();
  int tq = tid >> 6, ho = tid & 63;
  int t0 = tq * 8;
  #pragma unroll
  for (int l = 0; l < 3; ++l){
    float* cur = (l & 1) ? xb : xa;
    float* nxt = (l & 1) ? xa : xb;
    const float* wl = WT + l * 20480 + ho;
    float bv = bt[l * 64 + ho];
    float acc[8];
    #pragma unroll
    for (int r = 0; r < 8; ++r) acc[r] = bv;
    for (int ci = 0; ci < 64; ++ci){
      const float* xr = &cur[ci * 36 + t0];   // xr[q] = x[ci][t0+q-2]
      float4 x0 = *(const float4*)&xr[0];
      float4 x1 = *(const float4*)&xr[4];
      float4 x2 = *(const float4*)&xr[8];
      float xw[12] = {x0.x, x0.y, x0.z, x0.w, x1.x, x1.y, x1.z, x1.w,
                      x2.x, x2.y, x2.z, x2.w};
      const float* wp = wl + ci * 320;        // (ci*5+k)*64 + ho
      #pragma unroll
      for (int k = 0; k < 5; ++k){
        float w = wp[k * 64];
        #pragma unroll
        for (int r = 0; r < 8; ++r) acc[r] += xw[r + k] * w;
      }
    }
    #pragma unroll
    for (int r = 0; r < 8; ++r){
      int ti = t0 + r;
      nxt[ho * 36 + 2 + ti] = gelu_f(acc[r]) + cur[ho * 36 + 2 + ti];
    }
    __syncthreads();
  }
  float* fin = xb;   // after 3 layers result is in xb
  for (int i = tid; i < 2048; i += 256){
    int t = i >> 6, ch = i & 63;
    z[(size_t)(b * T_ + t) * NH_ + n * 64 + ch] = fin[ch * 36 + 2 + t];
  }
}

// MLP layer 1: grid (4 rowgroups = b, 128 kchunks of 185);
// each thread: 8 rows x 4 cols (32 FMA per W1 float4 load)
__global__ __launch_bounds__(256) void k_mlp1(const float* __restrict__ z,
    const float* __restrict__ W1, float* __restrict__ y1){
  __shared__ float zs[185 * 36];    // [j][r], r=0..31, stride 36
  int b = blockIdx.x;               // 0..3
  int kc = blockIdx.y;              // 0..127
  int base = kc * 185;
  int tid = threadIdx.x;
  for (int i = tid; i < 185 * 32; i += 256){
    int r = i / 185, j = i - r * 185;
    zs[j * 36 + r] = z[(size_t)(b * T_ + r) * NH_ + base + j];
  }
  __syncthreads();
  int r0 = (tid >> 6) * 8;
  int c0 = (tid & 63) * 4;
  float4 acc[8];
  #pragma unroll
  for (int r = 0; r < 8; ++r) acc[r] = (float4){0,0,0,0};
  const float* wbase = W1 + (size_t)base * 256 + c0;
  #pragma unroll 4
  for (int j = 0; j < 185; ++j){
    float4 wv = *(const float4*)&wbase[(size_t)j * 256];
    float4 za = *(const float4*)&zs[j * 36 + r0];
    float4 zb = *(const float4*)&zs[j * 36 + r0 + 4];
    acc[0].x += za.x*wv.x; acc[0].y += za.x*wv.y; acc[0].z += za.x*wv.z; acc[0].w += za.x*wv.w;
    acc[1].x += za.y*wv.x; acc[1].y += za.y*wv.y; acc[1].z += za.y*wv.z; acc[1].w += za.y*wv.w;
    acc[2].x += za.z*wv.x; acc[2].y += za.z*wv.y; acc[2].z += za.z*wv.z; acc[2].w += za.z*wv.w;
    acc[3].x += za.w*wv.x; acc[3].y += za.w*wv.y; acc[3].z += za.w*wv.z; acc[3].w += za.w*wv.w;
    acc[4].x += zb.x*wv.x; acc[4].y += zb.x*wv.y; acc[4].z += zb.x*wv.z; acc[4].w += zb.x*wv.w;
    acc[5].x += zb.y*wv.x; acc[5].y += zb.y*wv.y; acc[5].z += zb.y*wv.z; acc[5].w += zb.y*wv.w;
    acc[6].x += zb.z*wv.x; acc[6].y += zb.z*wv.y; acc[6].z += zb.z*wv.z; acc[6].w += zb.z*wv.w;
    acc[7].x += zb.w*wv.x; acc[7].y += zb.w*wv.y; acc[7].z += zb.w*wv.z; acc[7].w += zb.w*wv.w;
  }
  #pragma unroll
  for (int rr = 0; rr < 8; ++rr){
    int row = b * T_ + r0 + rr;
    float* yp = &y1[(size_t)row * 256 + c0];
    atomicAdd(&yp[0], acc[rr].x);
    atomicAdd(&yp[1], acc[rr].y);
    atomicAdd(&yp[2], acc[rr].z);
    atomicAdd(&yp[3], acc[rr].w);
  }
}

// MLP layer 2: out[128,64] = gelu(y1+b1) @ W2 + b2
__global__ __launch_bounds__(64) void k_mlp2(const float* __restrict__ y1,
    const float* __restrict__ b1, const float* __restrict__ W2,
    const float* __restrict__ b2, float* __restrict__ outp){
  __shared__ float a[256];
  int row = blockIdx.x, tid = threadIdx.x;
  for (int i = tid; i < 256; i += 64) a[i] = gelu_f(y1[(size_t)row * 256 + i] + b1[i]);
  __syncthreads();
  float acc = b2[tid];
  for (int i = 0; i < 256; ++i) acc += a[i] * W2[i * 64 + tid];
  outp[row * 64 + tid] = acc;
}

extern "C" void kernel_launch(void* const* d_in, const int* in_sizes, int n_in,
                              void* d_out, int out_size, void* d_ws, size_t ws_size,
                              hipStream_t stream){
  const float* x     = (const float*)d_in[0];
  const int*   ei    = (const int*)  d_in[1];
  const float* ew    = (const float*)d_in[2];
  const float* W_gcn = (const float*)d_in[3];
  const float* b_gcn = (const float*)d_in[4];
  const float* W_gat = (const float*)d_in[5];
  const float* att_s = (const float*)d_in[6];
  const float* att_d = (const float*)d_in[7];
  const float* b_gat = (const float*)d_in[8];
  const float* W_t   = (const float*)d_in[9];
  const float* b_t   = (const float*)d_in[10];
  const float* ln_g  = (const float*)d_in[11];
  const float* ln_b  = (const float*)d_in[12];
  const float* W1    = (const float*)d_in[13];
  const float* b1    = (const float*)d_in[14];
  const float* W2    = (const float*)d_in[15];
  const float* b2    = (const float*)d_in[16];
  float* outp = (float*)d_out;

  float* F = (float*)d_ws;
  size_t off = 0;
  float* deg    = F + off; off += 512;
  float* gnorm  = F + off; off += 12288;
  float* csr_g  = F + off; off += 12288;
  float* asrc   = F + off; off += 189440;
  float* adst   = F + off; off += 189440;
  float* invden = F + off; off += 189440;
  float* y1     = F + off; off += 32768;
  float* WT     = F + off; off += 61440;     // transposed temporal weights
  float* h      = F + off; off += 3031040;
  float* bufB   = F + off; off += 3031040;   // hw
  float* bufC   = F + off; off += 3031040;   // g
  float* bufD   = F + off; off += 3031040;   // gh / z
  float* alpha  = F + off; off += (size_t)G_ * E2_ * 4;   // 6,251,520
  int* I        = (int*)(F + off);
  int* counts   = I;
  int* offs     = I + 512;
  int* cursor   = I + 1024;
  int* csr_soff = I + 1536;                  // E2_ entries

  hipMemsetAsync(deg, 0, 512 * sizeof(float), stream);
  hipMemsetAsync(counts, 0, 512 * sizeof(int), stream);
  hipMemsetAsync(y1, 0, 32768 * sizeof(float), stream);

  k_deg_count<<<48, 256, 0, stream>>>(ei, ew, deg, counts);
  k_gnorm<<<48, 256, 0, stream>>>(ei, ew, deg, gnorm);
  k_scan<<<1, 64, 0, stream>>>(counts, offs, cursor);
  k_fill<<<48, 256, 0, stream>>>(ei, gnorm, cursor, csr_soff, csr_g);
  k_wtr<<<240, 256, 0, stream>>>(W_t, WT);
  hipMemcpyAsync(h, x, (size_t)GN_ * 64 * sizeof(float), hipMemcpyDeviceToDevice, stream);

  for (int l = 0; l < 3; ++l){
    k_rowgemm<<<740, 256, 0, stream>>>(h, W_gcn + l * 4096, bufB);
    k_gcn_agg<<<11840, 256, 0, stream>>>(bufB, csr_soff, offs, csr_g, b_gcn + l * 64, bufC);
    k_rowgemm<<<740, 256, 0, stream>>>(bufC, W_gat + l * 4096, bufD);
    k_attn<<<740, 256, 0, stream>>>(bufD, att_s + l * 64, att_d + l * 64, asrc, adst);
    k_alpha<<<740, 256, 0, stream>>>(asrc, adst, csr_soff, offs, alpha, invden);
    k_gat_agg<<<11840, 256, 0, stream>>>(bufD, alpha, invden, csr_soff, offs,
                                         b_gat + l * 64, ln_g + l * 64, ln_b + l * 64, h);
  }

  k_tfuse<<<BN_, 256, 0, stream>>>(h, WT, b_t, bufD);

  dim3 g1(4, 128);
  k_mlp1<<<g1, 256, 0, stream>>>(bufD, W1, y1);
  k_mlp2<<<128, 64, 0, stream>>>(y1, b1, W2, b2, outp);
}